// Round 1
// baseline (3776.005 us; speedup 1.0000x reference)
//
#include <hip/hip_runtime.h>
#include <hip/hip_bf16.h>

// Problem constants (from reference)
#define N_NODES 50000
#define E_EDGES 800000
#define DIN_K   384
#define DH_N    256
#define EPSN    1e-5f

// ---------------------------------------------------------------------------
// edge_attr column means (accumulate sums; stride is multiple of 32 so each
// thread always hits the same column = tid%32)
__global__ __launch_bounds__(256) void ea_accum_kernel(const float* __restrict__ ea,
                                                       float* __restrict__ accum, long total)
{
    long stride = (long)gridDim.x * blockDim.x;
    float local = 0.f;
    for (long i = (long)blockIdx.x * blockDim.x + threadIdx.x; i < total; i += stride)
        local += ea[i];
    __shared__ float red[256];
    red[threadIdx.x] = local;
    __syncthreads();
    if (threadIdx.x < 32) {
        float s = 0.f;
#pragma unroll
        for (int r = 0; r < 8; ++r) s += red[r * 32 + threadIdx.x];
        atomicAdd(&accum[threadIdx.x], s);
    }
}

// histogram of dst
__global__ void hist_kernel(const int* __restrict__ dst, int* __restrict__ counts, int E)
{
    int stride = gridDim.x * blockDim.x;
    for (int e = blockIdx.x * blockDim.x + threadIdx.x; e < E; e += stride)
        atomicAdd(&counts[dst[e]], 1);
}

// exclusive scan of counts -> offsets[N+1], single block
__global__ __launch_bounds__(1024) void scan_kernel(const int* __restrict__ counts,
                                                    int* __restrict__ offsets, int Nn)
{
    __shared__ int sdata[1024];
    __shared__ int run_s;
    int tid = threadIdx.x;
    if (tid == 0) run_s = 0;
    __syncthreads();
    for (int base2 = 0; base2 < Nn; base2 += 1024) {
        int i = base2 + tid;
        int v = (i < Nn) ? counts[i] : 0;
        sdata[tid] = v;
        __syncthreads();
        for (int off = 1; off < 1024; off <<= 1) {
            int t = (tid >= off) ? sdata[tid - off] : 0;
            __syncthreads();
            sdata[tid] += t;
            __syncthreads();
        }
        int run = run_s;
        if (i < Nn) offsets[i] = run + sdata[tid] - v;   // exclusive
        int tot = sdata[1023];
        __syncthreads();
        if (tid == 0) run_s = run + tot;
        __syncthreads();
    }
    if (tid == 0) offsets[Nn] = run_s;
}

// scatter edges into dst-sorted order
__global__ void scatter_kernel(const int* __restrict__ src, const int* __restrict__ dst,
                               const int* __restrict__ offsets, int* __restrict__ cursors,
                               int* __restrict__ s_src, int* __restrict__ s_eid, int E)
{
    int stride = gridDim.x * blockDim.x;
    for (int e = blockIdx.x * blockDim.x + threadIdx.x; e < E; e += stride) {
        int d = dst[e];
        int p = offsets[d] + atomicAdd(&cursors[d], 1);
        s_src[p] = src[e];
        s_eid[p] = e;
    }
}

// self-loop edge feature projections: eemean[layer] = (mean ea) @ We_layer
__global__ void eemean_kernel(const float* __restrict__ accum,
                              const float* __restrict__ We0, const float* __restrict__ We1,
                              float* __restrict__ eemean, float invE)
{
    int tid = threadIdx.x;          // 512 threads
    int layer = tid >> 8, c = tid & 255;
    const float* W = layer ? We1 : We0;
    float s = 0.f;
#pragma unroll
    for (int j = 0; j < 32; ++j) s += accum[j] * invE * W[j * 256 + c];
    eemean[layer * 256 + c] = s;
}

// ---------------------------------------------------------------------------
// fp32 tiled GEMM: C[M,Nn] = act(A[M,K] @ B[K,Nn] + bias). act: 0=none 1=relu
// BM=BN=64, BK=16, 256 threads, 4x4 per thread.
__global__ __launch_bounds__(256) void gemm_kernel(const float* __restrict__ A,
                                                   const float* __restrict__ B,
                                                   const float* __restrict__ bias,
                                                   float* __restrict__ C,
                                                   int M, int K, int Nn, int act)
{
    __shared__ float As[16][68];   // transposed A tile, padded stride (16B-aligned rows)
    __shared__ float Bs[16][64];
    int tid = threadIdx.x;
    int brow = blockIdx.x * 64;
    int bcol = blockIdx.y * 64;
    int tx = tid & 15, ty = tid >> 4;
    int arow = tid >> 2, akq = tid & 3;
    int bk = tid >> 4, bnq = tid & 15;
    float acc[4][4] = {};
    bool avalid = (brow + arow) < M;
    const float* Aptr = A + (size_t)(brow + arow) * K + akq * 4;
    const float* Bptr = B + (size_t)bk * Nn + bcol + bnq * 4;

    for (int k0 = 0; k0 < K; k0 += 16) {
        float4 a4 = make_float4(0.f, 0.f, 0.f, 0.f);
        if (avalid) a4 = *(const float4*)(Aptr + k0);
        float4 b4 = *(const float4*)(Bptr + (size_t)k0 * Nn);
        As[akq * 4 + 0][arow] = a4.x;
        As[akq * 4 + 1][arow] = a4.y;
        As[akq * 4 + 2][arow] = a4.z;
        As[akq * 4 + 3][arow] = a4.w;
        *(float4*)&Bs[bk][bnq * 4] = b4;
        __syncthreads();
#pragma unroll
        for (int kk = 0; kk < 16; ++kk) {
            float4 av = *(const float4*)&As[kk][ty * 4];
            float4 bv = *(const float4*)&Bs[kk][tx * 4];
            float aa[4] = {av.x, av.y, av.z, av.w};
            float bb[4] = {bv.x, bv.y, bv.z, bv.w};
#pragma unroll
            for (int i = 0; i < 4; ++i)
#pragma unroll
                for (int j = 0; j < 4; ++j)
                    acc[i][j] += aa[i] * bb[j];
        }
        __syncthreads();
    }
    float4 b4 = *(const float4*)&bias[bcol + tx * 4];
    float bb[4] = {b4.x, b4.y, b4.z, b4.w};
#pragma unroll
    for (int i = 0; i < 4; ++i) {
        int row = brow + ty * 4 + i;
        if (row < M) {
            float v[4];
#pragma unroll
            for (int j = 0; j < 4; ++j) {
                float t = acc[i][j] + bb[j];
                if (act == 1) t = t > 0.f ? t : 0.f;
                v[j] = t;
            }
            *(float4*)&C[(size_t)row * Nn + bcol + tx * 4] = make_float4(v[0], v[1], v[2], v[3]);
        }
    }
}

// ---------------------------------------------------------------------------
// One wave per dst node: fused ee = ea@We (We in LDS), GATv2 logits,
// online softmax, weighted xl accumulate, +bias, elu, y = h + hn (in place),
// and global sum/sumsq stats for graph_norm.
__global__ __launch_bounds__(256) void edge_attn_kernel(
    const int* __restrict__ s_src, const int* __restrict__ s_eid, const int* __restrict__ offsets,
    const float* __restrict__ ea, const float* __restrict__ We,
    const float* __restrict__ att, const float* __restrict__ bias, const float* __restrict__ eemean,
    const float* __restrict__ xl, const float* __restrict__ xr,
    float* __restrict__ h, float* __restrict__ stats)
{
    __shared__ float We_s[32 * 256];
    for (int i = threadIdx.x; i < 2048; i += 256)
        ((float4*)We_s)[i] = ((const float4*)We)[i];
    __syncthreads();

    int lane = threadIdx.x & 63;
    int d = blockIdx.x * 4 + (threadIdx.x >> 6);
    size_t base = (size_t)d * 256 + lane * 4;

    float4 xr4 = *(const float4*)(xr + base);
    float4 xls = *(const float4*)(xl + base);
    float4 eem = *(const float4*)(eemean + lane * 4);
    float4 at4 = *(const float4*)(att + (lane >> 4) * 64 + (lane & 15) * 4);

    float m = -1e30f, s = 0.f;
    float acc0 = 0.f, acc1 = 0.f, acc2 = 0.f, acc3 = 0.f;
    int beg = offsets[d], end = offsets[d + 1];

    for (int pos = beg; pos <= end; ++pos) {    // pos==end is the self-loop
        float xv0, xv1, xv2, xv3, e0, e1, e2, e3;
        if (pos < end) {
            int sn  = s_src[pos];
            int eid = s_eid[pos];
            float av = ea[(size_t)eid * 32 + (lane & 31)];
            e0 = e1 = e2 = e3 = 0.f;
#pragma unroll
            for (int j = 0; j < 32; ++j) {
                float aj = __shfl(av, j);
                float4 w4 = *(const float4*)&We_s[j * 256 + lane * 4];
                e0 += aj * w4.x; e1 += aj * w4.y; e2 += aj * w4.z; e3 += aj * w4.w;
            }
            float4 x4 = *(const float4*)(xl + (size_t)sn * 256 + lane * 4);
            xv0 = x4.x; xv1 = x4.y; xv2 = x4.z; xv3 = x4.w;
        } else {
            xv0 = xls.x; xv1 = xls.y; xv2 = xls.z; xv3 = xls.w;
            e0 = eem.x; e1 = eem.y; e2 = eem.z; e3 = eem.w;
        }
        float t0 = xv0 + xr4.x + e0; t0 = t0 > 0.f ? t0 : 0.2f * t0;
        float t1 = xv1 + xr4.y + e1; t1 = t1 > 0.f ? t1 : 0.2f * t1;
        float t2 = xv2 + xr4.z + e2; t2 = t2 > 0.f ? t2 : 0.2f * t2;
        float t3 = xv3 + xr4.w + e3; t3 = t3 > 0.f ? t3 : 0.2f * t3;
        float lg = t0 * at4.x + t1 * at4.y + t2 * at4.z + t3 * at4.w;
        lg += __shfl_xor(lg, 1);
        lg += __shfl_xor(lg, 2);
        lg += __shfl_xor(lg, 4);
        lg += __shfl_xor(lg, 8);        // 16-lane head group now all hold logit[h]
        float nm = fmaxf(m, lg);
        float sc = __expf(m - nm);
        float pr = __expf(lg - nm);
        s = s * sc + pr;
        acc0 = acc0 * sc + pr * xv0;
        acc1 = acc1 * sc + pr * xv1;
        acc2 = acc2 * sc + pr * xv2;
        acc3 = acc3 * sc + pr * xv3;
        m = nm;
    }

    float inv = 1.f / s;
    float4 b4 = *(const float4*)(bias + lane * 4);
    float4 hv = *(const float4*)(h + base);
    float o0 = acc0 * inv + b4.x; o0 = o0 > 0.f ? o0 : __expf(o0) - 1.f;
    float o1 = acc1 * inv + b4.y; o1 = o1 > 0.f ? o1 : __expf(o1) - 1.f;
    float o2 = acc2 * inv + b4.z; o2 = o2 > 0.f ? o2 : __expf(o2) - 1.f;
    float o3 = acc3 * inv + b4.w; o3 = o3 > 0.f ? o3 : __expf(o3) - 1.f;
    float y0 = hv.x + o0, y1 = hv.y + o1, y2 = hv.z + o2, y3 = hv.w + o3;
    *(float4*)(h + base) = make_float4(y0, y1, y2, y3);

    float ls = y0 + y1 + y2 + y3;
    float lq = y0 * y0 + y1 * y1 + y2 * y2 + y3 * y3;
#pragma unroll
    for (int o = 1; o < 64; o <<= 1) {
        ls += __shfl_xor(ls, o);
        lq += __shfl_xor(lq, o);
    }
    if (lane == 0) {
        atomicAdd(&stats[0], ls);
        atomicAdd(&stats[1], lq);
    }
}

// graph-norm scalars
__global__ void norm_finalize_kernel(float* __restrict__ stats)
{
    float invM = 1.f / ((float)N_NODES * 256.f);
    float mu = stats[0] * invM;
    float var = stats[1] * invM - mu * mu;
    stats[2] = mu;
    stats[3] = rsqrtf(var + EPSN);
}

// h = (h - mu) * scale * g[k] + beta[k], in place
__global__ void normalize_kernel(float* __restrict__ h, const float* __restrict__ g,
                                 const float* __restrict__ beta, const float* __restrict__ stats)
{
    float mu = stats[2], sc = stats[3];
    int stride = gridDim.x * blockDim.x;
    int total = N_NODES * 64;      // float4 count
    for (int i = blockIdx.x * blockDim.x + threadIdx.x; i < total; i += stride) {
        float4 v = ((float4*)h)[i];
        int k = (i & 63) * 4;
        float4 gv = *(const float4*)&g[k];
        float4 bv = *(const float4*)&beta[k];
        v.x = (v.x - mu) * sc * gv.x + bv.x;
        v.y = (v.y - mu) * sc * gv.y + bv.y;
        v.z = (v.z - mu) * sc * gv.z + bv.z;
        v.w = (v.w - mu) * sc * gv.w + bv.w;
        ((float4*)h)[i] = v;
    }
}

// ---------------------------------------------------------------------------
extern "C" void kernel_launch(void* const* d_in, const int* in_sizes, int n_in,
                              void* d_out, int out_size, void* d_ws, size_t ws_size,
                              hipStream_t stream)
{
    (void)in_sizes; (void)n_in; (void)out_size; (void)ws_size;
    // setup_inputs() dict order: x, edge_index, edge_attr, W_in, b_in, W_out, b_out,
    // then per layer: Wl, bl, Wr, br, We, att, bias, g, beta
    const float* x     = (const float*)d_in[0];
    const int*   eidx  = (const int*)d_in[1];
    const float* ea    = (const float*)d_in[2];
    const float* W_in  = (const float*)d_in[3];
    const float* b_in  = (const float*)d_in[4];
    const float* W_out = (const float*)d_in[5];
    const float* b_out = (const float*)d_in[6];
    const float* Wl[2]  = {(const float*)d_in[7],  (const float*)d_in[16]};
    const float* bl[2]  = {(const float*)d_in[8],  (const float*)d_in[17]};
    const float* Wr[2]  = {(const float*)d_in[9],  (const float*)d_in[18]};
    const float* br[2]  = {(const float*)d_in[10], (const float*)d_in[19]};
    const float* We[2]  = {(const float*)d_in[11], (const float*)d_in[20]};
    const float* att[2] = {(const float*)d_in[12], (const float*)d_in[21]};
    const float* bias[2]= {(const float*)d_in[13], (const float*)d_in[22]};
    const float* g[2]   = {(const float*)d_in[14], (const float*)d_in[23]};
    const float* beta[2]= {(const float*)d_in[15], (const float*)d_in[24]};

    // workspace layout (~161 MB)
    char* p = (char*)d_ws;
    auto take = [&](size_t bytes) -> char* {
        char* r = p;
        p += (bytes + 255) & ~(size_t)255;
        return r;
    };
    int*   counts  = (int*)take((size_t)N_NODES * 4);
    int*   cursors = (int*)take((size_t)N_NODES * 4);
    float* ea_acc  = (float*)take(32 * 4);
    float* stats   = (float*)take(8 * 4);
    size_t zero_bytes = (size_t)(p - (char*)d_ws);     // counts+cursors+ea_acc+stats
    int*   offsets = (int*)take((size_t)(N_NODES + 1) * 4);
    int*   s_src   = (int*)take((size_t)E_EDGES * 4);
    int*   s_eid   = (int*)take((size_t)E_EDGES * 4);
    float* eemean  = (float*)take(512 * 4);
    float* xl      = (float*)take((size_t)N_NODES * 256 * 4);
    float* xr      = (float*)take((size_t)N_NODES * 256 * 4);
    float* h       = (float*)take((size_t)N_NODES * 256 * 4);

    const int* srcv = eidx;
    const int* dstv = eidx + E_EDGES;

    hipMemsetAsync(d_ws, 0, zero_bytes, stream);

    ea_accum_kernel<<<512, 256, 0, stream>>>(ea, ea_acc, (long)E_EDGES * 32);
    hist_kernel<<<1024, 256, 0, stream>>>(dstv, counts, E_EDGES);
    scan_kernel<<<1, 1024, 0, stream>>>(counts, offsets, N_NODES);
    scatter_kernel<<<1024, 256, 0, stream>>>(srcv, dstv, offsets, cursors, s_src, s_eid, E_EDGES);
    eemean_kernel<<<1, 512, 0, stream>>>(ea_acc, We[0], We[1], eemean, 1.0f / (float)E_EDGES);

    dim3 ggrid((N_NODES + 63) / 64, 4);
    // h0 = relu(x @ W_in + b_in)
    gemm_kernel<<<ggrid, 256, 0, stream>>>(x, W_in, b_in, h, N_NODES, DIN_K, 256, 1);

    for (int l = 0; l < 2; ++l) {
        gemm_kernel<<<ggrid, 256, 0, stream>>>(h, Wl[l], bl[l], xl, N_NODES, 256, 256, 0);
        gemm_kernel<<<ggrid, 256, 0, stream>>>(h, Wr[l], br[l], xr, N_NODES, 256, 256, 0);
        edge_attn_kernel<<<N_NODES / 4, 256, 0, stream>>>(s_src, s_eid, offsets, ea, We[l],
                                                          att[l], bias[l], eemean + l * 256,
                                                          xl, xr, h, stats + l * 4);
        norm_finalize_kernel<<<1, 1, 0, stream>>>(stats + l * 4);
        normalize_kernel<<<2048, 256, 0, stream>>>(h, g[l], beta[l], stats + l * 4);
    }
    // out = h @ W_out + b_out
    gemm_kernel<<<ggrid, 256, 0, stream>>>(h, W_out, b_out, (float*)d_out, N_NODES, 256, 256, 0);
}

// Round 3
// 1917.369 us; speedup vs baseline: 1.9694x; 1.9694x over previous
//
#include <hip/hip_runtime.h>
#include <hip/hip_bf16.h>

// Problem constants (from reference)
#define N_NODES 50000
#define E_EDGES 800000
#define DIN_K   384
#define DH_N    256
#define EPSN    1e-5f

typedef unsigned short ushortT;

static __device__ __forceinline__ float bf2f(unsigned short u)
{
    return __uint_as_float(((unsigned)u) << 16);
}
static __device__ __forceinline__ unsigned short f2bf(float f)
{
    unsigned u = __float_as_uint(f);
    unsigned r = (u + 0x7fffu + ((u >> 16) & 1u)) >> 16;   // round-nearest-even
    return (unsigned short)r;
}

// ---------------------------------------------------------------------------
// edge_attr column sums (thread always hits column tid%32)
__global__ __launch_bounds__(256) void ea_accum_kernel(const float* __restrict__ ea,
                                                       float* __restrict__ accum, long total)
{
    long stride = (long)gridDim.x * blockDim.x;
    float local = 0.f;
    for (long i = (long)blockIdx.x * blockDim.x + threadIdx.x; i < total; i += stride)
        local += ea[i];
    __shared__ float red[256];
    red[threadIdx.x] = local;
    __syncthreads();
    if (threadIdx.x < 32) {
        float s = 0.f;
#pragma unroll
        for (int r = 0; r < 8; ++r) s += red[r * 32 + threadIdx.x];
        atomicAdd(&accum[threadIdx.x], s);
    }
}

// histogram of dst
__global__ void hist_kernel(const int* __restrict__ dst, int* __restrict__ counts, int E)
{
    int stride = gridDim.x * blockDim.x;
    for (int e = blockIdx.x * blockDim.x + threadIdx.x; e < E; e += stride)
        atomicAdd(&counts[dst[e]], 1);
}

// exclusive scan of counts -> offsets[N+1], single block
__global__ __launch_bounds__(1024) void scan_kernel(const int* __restrict__ counts,
                                                    int* __restrict__ offsets, int Nn)
{
    __shared__ int sdata[1024];
    __shared__ int run_s;
    int tid = threadIdx.x;
    if (tid == 0) run_s = 0;
    __syncthreads();
    for (int base2 = 0; base2 < Nn; base2 += 1024) {
        int i = base2 + tid;
        int v = (i < Nn) ? counts[i] : 0;
        sdata[tid] = v;
        __syncthreads();
        for (int off = 1; off < 1024; off <<= 1) {
            int t = (tid >= off) ? sdata[tid - off] : 0;
            __syncthreads();
            sdata[tid] += t;
            __syncthreads();
        }
        int run = run_s;
        if (i < Nn) offsets[i] = run + sdata[tid] - v;   // exclusive
        int tot = sdata[1023];
        __syncthreads();
        if (tid == 0) run_s = run + tot;
        __syncthreads();
    }
    if (tid == 0) offsets[Nn] = run_s;
}

// scatter edges into dst-sorted order
__global__ void scatter_kernel(const int* __restrict__ src, const int* __restrict__ dst,
                               const int* __restrict__ offsets, int* __restrict__ cursors,
                               int* __restrict__ s_src, int* __restrict__ s_dst,
                               int* __restrict__ s_eid, int E)
{
    int stride = gridDim.x * blockDim.x;
    for (int e = blockIdx.x * blockDim.x + threadIdx.x; e < E; e += stride) {
        int d = dst[e];
        int p = offsets[d] + atomicAdd(&cursors[d], 1);
        s_src[p] = src[e];
        s_dst[p] = d;
        s_eid[p] = e;
    }
}

// self-loop edge feature projections: eemean[layer] = (mean ea) @ We_layer
__global__ void eemean_kernel(const float* __restrict__ accum,
                              const float* __restrict__ We0, const float* __restrict__ We1,
                              float* __restrict__ eemean, float invE)
{
    int tid = threadIdx.x;          // 512 threads
    int layer = tid >> 8, c = tid & 255;
    const float* W = layer ? We1 : We0;
    float s = 0.f;
#pragma unroll
    for (int j = 0; j < 32; ++j) s += accum[j] * invE * W[j * 256 + c];
    eemean[layer * 256 + c] = s;
}

// ---------------------------------------------------------------------------
// fp32 tiled GEMM: C = act(A[M,K] @ B[K,Nn] + bias). act: 0=none 1=relu.
// outbf: 0 = fp32 C, 1 = bf16 (ushort) C.
__global__ __launch_bounds__(256) void gemm_kernel(const float* __restrict__ A,
                                                   const float* __restrict__ B,
                                                   const float* __restrict__ bias,
                                                   void* __restrict__ Cv,
                                                   int M, int K, int Nn, int act, int outbf)
{
    __shared__ float As[16][68];
    __shared__ float Bs[16][64];
    int tid = threadIdx.x;
    int brow = blockIdx.x * 64;
    int bcol = blockIdx.y * 64;
    int tx = tid & 15, ty = tid >> 4;
    int arow = tid >> 2, akq = tid & 3;
    int bk = tid >> 4, bnq = tid & 15;
    float acc[4][4] = {};
    bool avalid = (brow + arow) < M;
    const float* Aptr = A + (size_t)(brow + arow) * K + akq * 4;
    const float* Bptr = B + (size_t)bk * Nn + bcol + bnq * 4;

    for (int k0 = 0; k0 < K; k0 += 16) {
        float4 a4 = make_float4(0.f, 0.f, 0.f, 0.f);
        if (avalid) a4 = *(const float4*)(Aptr + k0);
        float4 b4 = *(const float4*)(Bptr + (size_t)k0 * Nn);
        As[akq * 4 + 0][arow] = a4.x;
        As[akq * 4 + 1][arow] = a4.y;
        As[akq * 4 + 2][arow] = a4.z;
        As[akq * 4 + 3][arow] = a4.w;
        *(float4*)&Bs[bk][bnq * 4] = b4;
        __syncthreads();
#pragma unroll
        for (int kk = 0; kk < 16; ++kk) {
            float4 av = *(const float4*)&As[kk][ty * 4];
            float4 bv = *(const float4*)&Bs[kk][tx * 4];
            float aa[4] = {av.x, av.y, av.z, av.w};
            float bb[4] = {bv.x, bv.y, bv.z, bv.w};
#pragma unroll
            for (int i = 0; i < 4; ++i)
#pragma unroll
                for (int j = 0; j < 4; ++j)
                    acc[i][j] += aa[i] * bb[j];
        }
        __syncthreads();
    }
    float4 b4 = *(const float4*)&bias[bcol + tx * 4];
    float bb[4] = {b4.x, b4.y, b4.z, b4.w};
#pragma unroll
    for (int i = 0; i < 4; ++i) {
        int row = brow + ty * 4 + i;
        if (row < M) {
            float v[4];
#pragma unroll
            for (int j = 0; j < 4; ++j) {
                float t = acc[i][j] + bb[j];
                if (act == 1) t = t > 0.f ? t : 0.f;
                v[j] = t;
            }
            if (outbf) {
                ushort4 o;
                o.x = f2bf(v[0]); o.y = f2bf(v[1]); o.z = f2bf(v[2]); o.w = f2bf(v[3]);
                *(ushort4*)((ushortT*)Cv + (size_t)row * Nn + bcol + tx * 4) = o;
            } else {
                *(float4*)((float*)Cv + (size_t)row * Nn + bcol + tx * 4) =
                    make_float4(v[0], v[1], v[2], v[3]);
            }
        }
    }
}

// ---------------------------------------------------------------------------
// Per-edge logits: for sorted edge p with (src,dst,eid):
//   ee = ea[eid] @ We  (K=32, exact fp32, GEMM in LDS)
//   m  = leaky_relu(xl[src] + xr[dst] + ee, 0.2)   (xl/xr bf16 tables)
//   logits[p*4+h] = sum_c m[h*64+c] * att[h*64+c]
// Block: 256 threads = 64 edges x 256 cols; thread tile 4 edges x 16 cols.
__global__ __launch_bounds__(256) void edge_logits_kernel(
    const float* __restrict__ ea, const int* __restrict__ s_eid,
    const int* __restrict__ s_src, const int* __restrict__ s_dst,
    const float* __restrict__ We, const float* __restrict__ att,
    const ushortT* __restrict__ xl, const ushortT* __restrict__ xr,
    float* __restrict__ logits)
{
    __shared__ float As[32][68];     // K x 64 edges (transposed), padded
    __shared__ float Bs[32][256];    // K x 256 cols of We (32 KB)
    __shared__ int   sidx[64], didx[64];
    int tid = threadIdx.x;
    int brow = blockIdx.x * 64;

    // load We tile: 2048 float4, 8 per thread
#pragma unroll
    for (int t = 0; t < 8; ++t) {
        int f4 = tid + t * 256;
        int kr = f4 >> 6, cq = f4 & 63;
        *(float4*)&Bs[kr][cq * 4] = *(const float4*)(We + (size_t)kr * 256 + cq * 4);
    }
    // gather ea rows: 512 float4, 2 per thread
#pragma unroll
    for (int t = 0; t < 2; ++t) {
        int f4 = tid + t * 256;
        int row = f4 >> 3, colq = f4 & 7;
        int ge = s_eid[brow + row];
        float4 a4 = *(const float4*)(ea + (size_t)ge * 32 + colq * 4);
        As[colq * 4 + 0][row] = a4.x;
        As[colq * 4 + 1][row] = a4.y;
        As[colq * 4 + 2][row] = a4.z;
        As[colq * 4 + 3][row] = a4.w;
    }
    if (tid < 64) { sidx[tid] = s_src[brow + tid]; didx[tid] = s_dst[brow + tid]; }
    __syncthreads();

    int tx = tid & 15, ty = tid >> 4;
    float acc[4][16] = {};
#pragma unroll 4
    for (int kk = 0; kk < 32; ++kk) {
        float a[4];
#pragma unroll
        for (int i = 0; i < 4; ++i) a[i] = As[kk][ty * 4 + i];
        float b[16];
#pragma unroll
        for (int q = 0; q < 4; ++q)
            *(float4*)&b[q * 4] = *(const float4*)&Bs[kk][tx * 16 + q * 4];
#pragma unroll
        for (int i = 0; i < 4; ++i)
#pragma unroll
            for (int j = 0; j < 16; ++j)
                acc[i][j] += a[i] * b[j];
    }

    float att_r[16];
#pragma unroll
    for (int q = 0; q < 4; ++q)
        *(float4*)&att_r[q * 4] = *(const float4*)(att + tx * 16 + q * 4);
    int head = tx >> 2;

#pragma unroll
    for (int i = 0; i < 4; ++i) {
        int e = ty * 4 + i;
        int sn = sidx[e], dn = didx[e];
        float part = 0.f;
#pragma unroll
        for (int q = 0; q < 4; ++q) {
            ushort4 lx = *(const ushort4*)(xl + (size_t)sn * 256 + tx * 16 + q * 4);
            ushort4 rx = *(const ushort4*)(xr + (size_t)dn * 256 + tx * 16 + q * 4);
            float l0 = bf2f(lx.x), l1 = bf2f(lx.y), l2 = bf2f(lx.z), l3 = bf2f(lx.w);
            float r0 = bf2f(rx.x), r1 = bf2f(rx.y), r2 = bf2f(rx.z), r3 = bf2f(rx.w);
            float t0 = acc[i][q * 4 + 0] + l0 + r0; t0 = t0 > 0.f ? t0 : 0.2f * t0;
            float t1 = acc[i][q * 4 + 1] + l1 + r1; t1 = t1 > 0.f ? t1 : 0.2f * t1;
            float t2 = acc[i][q * 4 + 2] + l2 + r2; t2 = t2 > 0.f ? t2 : 0.2f * t2;
            float t3 = acc[i][q * 4 + 3] + l3 + r3; t3 = t3 > 0.f ? t3 : 0.2f * t3;
            part += t0 * att_r[q * 4 + 0] + t1 * att_r[q * 4 + 1]
                  + t2 * att_r[q * 4 + 2] + t3 * att_r[q * 4 + 3];
        }
        // sum over the 4 tx values belonging to this head (lane bits 0,1)
        part += __shfl_xor(part, 1);
        part += __shfl_xor(part, 2);
        if ((tx & 3) == 0)
            logits[(size_t)(brow + e) * 4 + head] = part;
    }
}

// ---------------------------------------------------------------------------
// One wave per dst node: stream sorted logits, online softmax, gather bf16
// xl[src] for weighted accumulate, +bias, elu, y = h + hn (in place).
__global__ __launch_bounds__(256) void edge_attn_kernel(
    const int* __restrict__ s_src, const int* __restrict__ offsets,
    const float* __restrict__ logits,
    const float* __restrict__ att, const float* __restrict__ bias,
    const float* __restrict__ eemean,
    const ushortT* __restrict__ xl, const ushortT* __restrict__ xr,
    float* __restrict__ h)
{
    int lane = threadIdx.x & 63;
    int d = blockIdx.x * 4 + (threadIdx.x >> 6);
    size_t base = (size_t)d * 256 + lane * 4;
    int head = lane >> 4;

    ushort4 xru = *(const ushort4*)(xr + base);
    ushort4 xlu = *(const ushort4*)(xl + base);
    float xr0 = bf2f(xru.x), xr1 = bf2f(xru.y), xr2 = bf2f(xru.z), xr3 = bf2f(xru.w);
    float xs0 = bf2f(xlu.x), xs1 = bf2f(xlu.y), xs2 = bf2f(xlu.z), xs3 = bf2f(xlu.w);
    float4 eem = *(const float4*)(eemean + lane * 4);
    float4 at4 = *(const float4*)(att + lane * 4);

    float m = -1e30f, s = 0.f;
    float acc0 = 0.f, acc1 = 0.f, acc2 = 0.f, acc3 = 0.f;
    int beg = offsets[d], end = offsets[d + 1];

    // prefetch pipeline: depth-2 for index, depth-1 for data
    int idx1 = 0;
    ushort4 x_cur = make_ushort4(0, 0, 0, 0);
    float lg_cur = 0.f;
    if (beg < end) {
        int idx0 = s_src[beg];
        x_cur = *(const ushort4*)(xl + (size_t)idx0 * 256 + lane * 4);
        lg_cur = logits[(size_t)beg * 4 + head];
        if (beg + 1 < end) idx1 = s_src[beg + 1];
    }

    for (int pos = beg; pos < end; ++pos) {
        ushort4 xv = x_cur;
        float lg = lg_cur;
        int np = pos + 1;
        if (np < end) {
            x_cur = *(const ushort4*)(xl + (size_t)idx1 * 256 + lane * 4);
            lg_cur = logits[(size_t)np * 4 + head];
        }
        if (pos + 2 < end) idx1 = s_src[pos + 2];

        float nm = fmaxf(m, lg);
        float sc = __expf(m - nm);
        float pr = __expf(lg - nm);
        float v0 = bf2f(xv.x), v1 = bf2f(xv.y), v2 = bf2f(xv.z), v3 = bf2f(xv.w);
        s = s * sc + pr;
        acc0 = acc0 * sc + pr * v0;
        acc1 = acc1 * sc + pr * v1;
        acc2 = acc2 * sc + pr * v2;
        acc3 = acc3 * sc + pr * v3;
        m = nm;
    }

    // self-loop edge (xl[d], eemean)
    {
        float t0 = xs0 + xr0 + eem.x; t0 = t0 > 0.f ? t0 : 0.2f * t0;
        float t1 = xs1 + xr1 + eem.y; t1 = t1 > 0.f ? t1 : 0.2f * t1;
        float t2 = xs2 + xr2 + eem.z; t2 = t2 > 0.f ? t2 : 0.2f * t2;
        float t3 = xs3 + xr3 + eem.w; t3 = t3 > 0.f ? t3 : 0.2f * t3;
        float lg = t0 * at4.x + t1 * at4.y + t2 * at4.z + t3 * at4.w;
        lg += __shfl_xor(lg, 1);
        lg += __shfl_xor(lg, 2);
        lg += __shfl_xor(lg, 4);
        lg += __shfl_xor(lg, 8);        // 16-lane head group holds the logit
        float nm = fmaxf(m, lg);
        float sc = __expf(m - nm);
        float pr = __expf(lg - nm);
        s = s * sc + pr;
        acc0 = acc0 * sc + pr * xs0;
        acc1 = acc1 * sc + pr * xs1;
        acc2 = acc2 * sc + pr * xs2;
        acc3 = acc3 * sc + pr * xs3;
    }

    float inv = 1.f / s;
    float4 b4 = *(const float4*)(bias + lane * 4);
    float4 hv = *(const float4*)(h + base);
    float o0 = acc0 * inv + b4.x; o0 = o0 > 0.f ? o0 : __expf(o0) - 1.f;
    float o1 = acc1 * inv + b4.y; o1 = o1 > 0.f ? o1 : __expf(o1) - 1.f;
    float o2 = acc2 * inv + b4.z; o2 = o2 > 0.f ? o2 : __expf(o2) - 1.f;
    float o3 = acc3 * inv + b4.w; o3 = o3 > 0.f ? o3 : __expf(o3) - 1.f;
    *(float4*)(h + base) = make_float4(hv.x + o0, hv.y + o1, hv.z + o2, hv.w + o3);
}

// ---------------------------------------------------------------------------
// graph-norm stats: sum and sumsq of h, one atomic pair per block
__global__ __launch_bounds__(256) void stats_kernel(const float* __restrict__ h,
                                                    float* __restrict__ stats)
{
    int stride = gridDim.x * blockDim.x;
    int total = N_NODES * 64;      // float4 count
    float ls = 0.f, lq = 0.f;
    for (int i = blockIdx.x * blockDim.x + threadIdx.x; i < total; i += stride) {
        float4 v = ((const float4*)h)[i];
        ls += v.x + v.y + v.z + v.w;
        lq += v.x * v.x + v.y * v.y + v.z * v.z + v.w * v.w;
    }
#pragma unroll
    for (int o = 1; o < 64; o <<= 1) {
        ls += __shfl_xor(ls, o);
        lq += __shfl_xor(lq, o);
    }
    __shared__ float red[8];
    int lane = threadIdx.x & 63, w = threadIdx.x >> 6;
    if (lane == 0) { red[w * 2] = ls; red[w * 2 + 1] = lq; }
    __syncthreads();
    if (threadIdx.x == 0) {
        atomicAdd(&stats[0], red[0] + red[2] + red[4] + red[6]);
        atomicAdd(&stats[1], red[1] + red[3] + red[5] + red[7]);
    }
}

// graph-norm scalars
__global__ void norm_finalize_kernel(float* __restrict__ stats)
{
    float invM = 1.f / ((float)N_NODES * 256.f);
    float mu = stats[0] * invM;
    float var = stats[1] * invM - mu * mu;
    stats[2] = mu;
    stats[3] = rsqrtf(var + EPSN);
}

// h = (h - mu) * scale * g[k] + beta[k], in place
__global__ void normalize_kernel(float* __restrict__ h, const float* __restrict__ g,
                                 const float* __restrict__ beta, const float* __restrict__ stats)
{
    float mu = stats[2], sc = stats[3];
    int stride = gridDim.x * blockDim.x;
    int total = N_NODES * 64;      // float4 count
    for (int i = blockIdx.x * blockDim.x + threadIdx.x; i < total; i += stride) {
        float4 v = ((float4*)h)[i];
        int k = (i & 63) * 4;
        float4 gv = *(const float4*)&g[k];
        float4 bv = *(const float4*)&beta[k];
        v.x = (v.x - mu) * sc * gv.x + bv.x;
        v.y = (v.y - mu) * sc * gv.y + bv.y;
        v.z = (v.z - mu) * sc * gv.z + bv.z;
        v.w = (v.w - mu) * sc * gv.w + bv.w;
        ((float4*)h)[i] = v;
    }
}

// ---------------------------------------------------------------------------
extern "C" void kernel_launch(void* const* d_in, const int* in_sizes, int n_in,
                              void* d_out, int out_size, void* d_ws, size_t ws_size,
                              hipStream_t stream)
{
    (void)in_sizes; (void)n_in; (void)out_size; (void)ws_size;
    const float* x     = (const float*)d_in[0];
    const int*   eidx  = (const int*)d_in[1];
    const float* ea    = (const float*)d_in[2];
    const float* W_in  = (const float*)d_in[3];
    const float* b_in  = (const float*)d_in[4];
    const float* W_out = (const float*)d_in[5];
    const float* b_out = (const float*)d_in[6];
    const float* Wl[2]  = {(const float*)d_in[7],  (const float*)d_in[16]};
    const float* bl[2]  = {(const float*)d_in[8],  (const float*)d_in[17]};
    const float* Wr[2]  = {(const float*)d_in[9],  (const float*)d_in[18]};
    const float* br[2]  = {(const float*)d_in[10], (const float*)d_in[19]};
    const float* We[2]  = {(const float*)d_in[11], (const float*)d_in[20]};
    const float* att[2] = {(const float*)d_in[12], (const float*)d_in[21]};
    const float* bias[2]= {(const float*)d_in[13], (const float*)d_in[22]};
    const float* g[2]   = {(const float*)d_in[14], (const float*)d_in[23]};
    const float* beta[2]= {(const float*)d_in[15], (const float*)d_in[24]};

    // workspace layout (~126 MB; known-safe envelope is >= 161 MB)
    char* p = (char*)d_ws;
    auto take = [&](size_t bytes) -> char* {
        char* r = p;
        p += (bytes + 255) & ~(size_t)255;
        return r;
    };
    int*   counts  = (int*)take((size_t)N_NODES * 4);
    int*   cursors = (int*)take((size_t)N_NODES * 4);
    float* ea_acc  = (float*)take(32 * 4);
    float* stats   = (float*)take(8 * 4);
    size_t zero_bytes = (size_t)(p - (char*)d_ws);     // counts+cursors+ea_acc+stats
    int*   offsets = (int*)take((size_t)(N_NODES + 1) * 4);
    int*   s_src   = (int*)take((size_t)E_EDGES * 4);
    int*   s_dst   = (int*)take((size_t)E_EDGES * 4);
    int*   s_eid   = (int*)take((size_t)E_EDGES * 4);
    float* eemean  = (float*)take(512 * 4);
    ushortT* xl    = (ushortT*)take((size_t)N_NODES * 256 * 2);
    ushortT* xr    = (ushortT*)take((size_t)N_NODES * 256 * 2);
    float* h       = (float*)take((size_t)N_NODES * 256 * 4);
    float* logits  = (float*)take((size_t)E_EDGES * 4 * 4);

    const int* srcv = eidx;
    const int* dstv = eidx + E_EDGES;

    hipMemsetAsync(d_ws, 0, zero_bytes, stream);

    ea_accum_kernel<<<512, 256, 0, stream>>>(ea, ea_acc, (long)E_EDGES * 32);
    hist_kernel<<<1024, 256, 0, stream>>>(dstv, counts, E_EDGES);
    scan_kernel<<<1, 1024, 0, stream>>>(counts, offsets, N_NODES);
    scatter_kernel<<<1024, 256, 0, stream>>>(srcv, dstv, offsets, cursors,
                                             s_src, s_dst, s_eid, E_EDGES);
    eemean_kernel<<<1, 512, 0, stream>>>(ea_acc, We[0], We[1], eemean, 1.0f / (float)E_EDGES);

    dim3 ggrid((N_NODES + 63) / 64, 4);
    // h0 = relu(x @ W_in + b_in), fp32
    gemm_kernel<<<ggrid, 256, 0, stream>>>(x, W_in, b_in, h, N_NODES, DIN_K, 256, 1, 0);

    for (int l = 0; l < 2; ++l) {
        gemm_kernel<<<ggrid, 256, 0, stream>>>(h, Wl[l], bl[l], xl, N_NODES, 256, 256, 0, 1);
        gemm_kernel<<<ggrid, 256, 0, stream>>>(h, Wr[l], br[l], xr, N_NODES, 256, 256, 0, 1);
        edge_logits_kernel<<<E_EDGES / 64, 256, 0, stream>>>(ea, s_eid, s_src, s_dst,
                                                             We[l], att[l], xl, xr, logits);
        edge_attn_kernel<<<N_NODES / 4, 256, 0, stream>>>(s_src, offsets, logits,
                                                          att[l], bias[l], eemean + l * 256,
                                                          xl, xr, h);
        stats_kernel<<<2048, 256, 0, stream>>>(h, stats + l * 4);
        norm_finalize_kernel<<<1, 1, 0, stream>>>(stats + l * 4);
        normalize_kernel<<<2048, 256, 0, stream>>>(h, g[l], beta[l], stats + l * 4);
    }
    // out = h @ W_out + b_out, fp32
    gemm_kernel<<<ggrid, 256, 0, stream>>>(h, W_out, b_out, (float*)d_out, N_NODES, 256, 256, 0, 0);
}

// Round 4
// 1488.937 us; speedup vs baseline: 2.5360x; 1.2877x over previous
//
#include <hip/hip_runtime.h>
#include <hip/hip_bf16.h>

// Problem constants (from reference)
#define N_NODES 50000
#define E_EDGES 800000
#define DIN_K   384
#define DH_N    256
#define EPSN    1e-5f

typedef unsigned short ushortT;
typedef __attribute__((ext_vector_type(4))) float f32x4;
typedef __attribute__((ext_vector_type(8))) short bf16x8;

static __device__ __forceinline__ float bf2f(unsigned short u)
{
    return __uint_as_float(((unsigned)u) << 16);
}
static __device__ __forceinline__ unsigned short f2bf(float f)
{
    unsigned u = __float_as_uint(f);
    unsigned r = (u + 0x7fffu + ((u >> 16) & 1u)) >> 16;   // round-nearest-even
    return (unsigned short)r;
}
static __device__ __forceinline__ unsigned pack2(float a, float b)
{
    return (unsigned)f2bf(a) | ((unsigned)f2bf(b) << 16);
}

// ---------------------------------------------------------------------------
// edge_attr column sums (thread always hits column tid%32)
__global__ __launch_bounds__(256) void ea_accum_kernel(const float* __restrict__ ea,
                                                       float* __restrict__ accum, long total)
{
    long stride = (long)gridDim.x * blockDim.x;
    float local = 0.f;
    for (long i = (long)blockIdx.x * blockDim.x + threadIdx.x; i < total; i += stride)
        local += ea[i];
    __shared__ float red[256];
    red[threadIdx.x] = local;
    __syncthreads();
    if (threadIdx.x < 32) {
        float s = 0.f;
#pragma unroll
        for (int r = 0; r < 8; ++r) s += red[r * 32 + threadIdx.x];
        atomicAdd(&accum[threadIdx.x], s);
    }
}

// histogram of dst
__global__ void hist_kernel(const int* __restrict__ dst, int* __restrict__ counts, int E)
{
    int stride = gridDim.x * blockDim.x;
    for (int e = blockIdx.x * blockDim.x + threadIdx.x; e < E; e += stride)
        atomicAdd(&counts[dst[e]], 1);
}

// exclusive scan of counts -> offsets[N+1], single block
__global__ __launch_bounds__(1024) void scan_kernel(const int* __restrict__ counts,
                                                    int* __restrict__ offsets, int Nn)
{
    __shared__ int sdata[1024];
    __shared__ int run_s;
    int tid = threadIdx.x;
    if (tid == 0) run_s = 0;
    __syncthreads();
    for (int base2 = 0; base2 < Nn; base2 += 1024) {
        int i = base2 + tid;
        int v = (i < Nn) ? counts[i] : 0;
        sdata[tid] = v;
        __syncthreads();
        for (int off = 1; off < 1024; off <<= 1) {
            int t = (tid >= off) ? sdata[tid - off] : 0;
            __syncthreads();
            sdata[tid] += t;
            __syncthreads();
        }
        int run = run_s;
        if (i < Nn) offsets[i] = run + sdata[tid] - v;   // exclusive
        int tot = sdata[1023];
        __syncthreads();
        if (tid == 0) run_s = run + tot;
        __syncthreads();
    }
    if (tid == 0) offsets[Nn] = run_s;
}

// scatter edges into dst-sorted order
__global__ void scatter_kernel(const int* __restrict__ src, const int* __restrict__ dst,
                               const int* __restrict__ offsets, int* __restrict__ cursors,
                               int* __restrict__ s_src, int* __restrict__ s_dst,
                               int* __restrict__ s_eid, int E)
{
    int stride = gridDim.x * blockDim.x;
    for (int e = blockIdx.x * blockDim.x + threadIdx.x; e < E; e += stride) {
        int d = dst[e];
        int p = offsets[d] + atomicAdd(&cursors[d], 1);
        s_src[p] = src[e];
        s_dst[p] = d;
        s_eid[p] = e;
    }
}

// self-loop edge feature projections: eemean[layer] = (mean ea) @ We_layer
__global__ void eemean_kernel(const float* __restrict__ accum,
                              const float* __restrict__ We0, const float* __restrict__ We1,
                              float* __restrict__ eemean, float invE)
{
    int tid = threadIdx.x;          // 512 threads
    int layer = tid >> 8, c = tid & 255;
    const float* W = layer ? We1 : We0;
    float s = 0.f;
#pragma unroll
    for (int j = 0; j < 32; ++j) s += accum[j] * invE * W[j * 256 + c];
    eemean[layer * 256 + c] = s;
}

// ---------------------------------------------------------------------------
// weight transpose + bf16 convert: out[n][k] = bf16(in[k][n]); in is [K][N]
__global__ __launch_bounds__(256) void transpose_bf16_kernel(const float* __restrict__ in,
                                                             ushortT* __restrict__ out,
                                                             int K, int N)
{
    __shared__ float tile[32][33];
    int bx = blockIdx.x * 32;     // N dim
    int by = blockIdx.y * 32;     // K dim
    int tx = threadIdx.x & 31, ty = threadIdx.x >> 5;
#pragma unroll
    for (int r = 0; r < 32; r += 8) {
        int k = by + ty + r, n = bx + tx;
        if (k < K && n < N) tile[ty + r][tx] = in[(size_t)k * N + n];
    }
    __syncthreads();
#pragma unroll
    for (int r = 0; r < 32; r += 8) {
        int n = bx + ty + r, k = by + tx;
        if (n < N && k < K) out[(size_t)n * K + k] = f2bf(tile[tx][ty + r]);
    }
}

// fused bias [512] = bl | br
__global__ void fuse_bias_kernel(const float* __restrict__ bl, const float* __restrict__ br,
                                 float* __restrict__ out)
{
    int i = threadIdx.x;
    out[i] = (i < 256) ? bl[i] : br[i - 256];
}

// ---------------------------------------------------------------------------
// MFMA bf16 GEMM: C[row,col] = act(A[row,:K] @ Bt[col,:K]^T + bias[col])
// A fp32 [>=Mvalid][K] (staged->bf16), Bt bf16 [Nn][K] (pre-transposed weights).
// 128x128 tile, BK=32, 256 threads = 4 waves (2x2), 16 mfma_16x16x32 per wave/step.
// Outputs: Cf fp32 and/or Cb bf16 (either may be null). Rows guarded at N_NODES.
__global__ __launch_bounds__(256) void mfma_gemm_kernel(
    const float* __restrict__ A, const ushortT* __restrict__ Bt,
    const float* __restrict__ bias, float* __restrict__ Cf,
    ushortT* __restrict__ Cb, int K, int Nn, int act)
{
    __shared__ __align__(16) ushortT As[128 * 32];
    __shared__ __align__(16) ushortT Bs[128 * 32];
    int tid = threadIdx.x;
    int brow = blockIdx.x * 128;
    int bcol = blockIdx.y * 128;
    int lane = tid & 63, w = tid >> 6;
    int wr = w >> 1, wc = w & 1;
    int fr = lane & 15, fq = lane >> 4;

    f32x4 acc[4][4];
#pragma unroll
    for (int i = 0; i < 4; ++i)
#pragma unroll
        for (int j = 0; j < 4; ++j)
            acc[i][j] = (f32x4){0.f, 0.f, 0.f, 0.f};

    // staging: chunk c (c = tid, tid+256) covers LDS row c>>2, k-group c&3
    // (8 bf16 = 16B at LDS byte c*16) -> lane-linear b128 writes, no conflicts
    int r0 = tid >> 2, g0 = tid & 3;
    int r1 = r0 + 64;
    int arow0 = brow + r0, arow1 = brow + r1;
    bool av0 = arow0 < N_NODES, av1 = arow1 < N_NODES;
    const float* Ap0 = A + (size_t)arow0 * K + g0 * 8;
    const float* Ap1 = A + (size_t)arow1 * K + g0 * 8;
    const ushortT* Bp0 = Bt + (size_t)(bcol + r0) * K + g0 * 8;
    const ushortT* Bp1 = Bt + (size_t)(bcol + r1) * K + g0 * 8;
    uint4* asw0 = (uint4*)&As[(size_t)tid * 8];
    uint4* asw1 = (uint4*)&As[(size_t)(tid + 256) * 8];
    uint4* bsw0 = (uint4*)&Bs[(size_t)tid * 8];
    uint4* bsw1 = (uint4*)&Bs[(size_t)(tid + 256) * 8];

    for (int k0 = 0; k0 < K; k0 += 32) {
        float4 z = make_float4(0.f, 0.f, 0.f, 0.f);
        float4 fa0 = z, fa1 = z, fc0 = z, fc1 = z;
        if (av0) { fa0 = *(const float4*)(Ap0 + k0); fc0 = *(const float4*)(Ap0 + k0 + 4); }
        if (av1) { fa1 = *(const float4*)(Ap1 + k0); fc1 = *(const float4*)(Ap1 + k0 + 4); }
        uint4 ub0 = *(const uint4*)(Bp0 + k0);
        uint4 ub1 = *(const uint4*)(Bp1 + k0);
        uint4 ua0, ua1;
        ua0.x = pack2(fa0.x, fa0.y); ua0.y = pack2(fa0.z, fa0.w);
        ua0.z = pack2(fc0.x, fc0.y); ua0.w = pack2(fc0.z, fc0.w);
        ua1.x = pack2(fa1.x, fa1.y); ua1.y = pack2(fa1.z, fa1.w);
        ua1.z = pack2(fc1.x, fc1.y); ua1.w = pack2(fc1.z, fc1.w);
        __syncthreads();           // prior iteration's frag reads complete
        *asw0 = ua0; *asw1 = ua1;
        *bsw0 = ub0; *bsw1 = ub1;
        __syncthreads();

        bf16x8 af[4], bfv[4];
#pragma unroll
        for (int mi = 0; mi < 4; ++mi)
            af[mi] = *(bf16x8*)&As[(size_t)(wr * 64 + mi * 16 + fr) * 32 + fq * 8];
#pragma unroll
        for (int ni = 0; ni < 4; ++ni)
            bfv[ni] = *(bf16x8*)&Bs[(size_t)(wc * 64 + ni * 16 + fr) * 32 + fq * 8];
#pragma unroll
        for (int mi = 0; mi < 4; ++mi)
#pragma unroll
            for (int ni = 0; ni < 4; ++ni)
                acc[mi][ni] = __builtin_amdgcn_mfma_f32_16x16x32_bf16(
                    af[mi], bfv[ni], acc[mi][ni], 0, 0, 0);
    }

    // epilogue: C frag mapping col=lane&15, row=(lane>>4)*4+reg (m89-verified)
#pragma unroll
    for (int ni = 0; ni < 4; ++ni) {
        int col = bcol + wc * 64 + ni * 16 + fr;
        float bv = bias[col];
#pragma unroll
        for (int mi = 0; mi < 4; ++mi) {
#pragma unroll
            for (int r = 0; r < 4; ++r) {
                int row = brow + wr * 64 + mi * 16 + fq * 4 + r;
                if (row < N_NODES) {
                    float t = acc[mi][ni][r] + bv;
                    if (act == 1) t = t > 0.f ? t : 0.f;
                    if (Cf) Cf[(size_t)row * Nn + col] = t;
                    if (Cb) Cb[(size_t)row * Nn + col] = f2bf(t);
                }
            }
        }
    }
}

// ---------------------------------------------------------------------------
// Per-edge logits: ee = ea[eid] @ We (exact fp32); m = leaky(xl[src]+xr[dst]+ee);
// logits[p*4+h] = sum_c m[h*64+c]*att[h*64+c].  xlr packed [node][512] bf16:
// cols 0-255 = xl, 256-511 = xr.
__global__ __launch_bounds__(256) void edge_logits_kernel(
    const float* __restrict__ ea, const int* __restrict__ s_eid,
    const int* __restrict__ s_src, const int* __restrict__ s_dst,
    const float* __restrict__ We, const float* __restrict__ att,
    const ushortT* __restrict__ xlr, float* __restrict__ logits)
{
    __shared__ float As[32][68];     // K x 64 edges (transposed), padded
    __shared__ float Bs[32][256];    // K x 256 cols of We, float4-groups laid [q][tx]
    __shared__ int   sidx[64], didx[64];
    int tid = threadIdx.x;
    int brow = blockIdx.x * 64;

    // load We tile: float4 group cq stored at [(cq&3)*64 + (cq>>2)*4]
#pragma unroll
    for (int t = 0; t < 8; ++t) {
        int f4 = tid + t * 256;
        int kr = f4 >> 6, cq = f4 & 63;
        *(float4*)&Bs[kr][(cq & 3) * 64 + (cq >> 2) * 4] =
            *(const float4*)(We + (size_t)kr * 256 + cq * 4);
    }
    // gather ea rows: 512 float4, 2 per thread
#pragma unroll
    for (int t = 0; t < 2; ++t) {
        int f4 = tid + t * 256;
        int row = f4 >> 3, colq = f4 & 7;
        int ge = s_eid[brow + row];
        float4 a4 = *(const float4*)(ea + (size_t)ge * 32 + colq * 4);
        As[colq * 4 + 0][row] = a4.x;
        As[colq * 4 + 1][row] = a4.y;
        As[colq * 4 + 2][row] = a4.z;
        As[colq * 4 + 3][row] = a4.w;
    }
    if (tid < 64) { sidx[tid] = s_src[brow + tid]; didx[tid] = s_dst[brow + tid]; }
    __syncthreads();

    int tx = tid & 15, ty = tid >> 4;
    float acc[4][16] = {};
#pragma unroll 4
    for (int kk = 0; kk < 32; ++kk) {
        float a[4];
#pragma unroll
        for (int i = 0; i < 4; ++i) a[i] = As[kk][ty * 4 + i];
        float b[16];
#pragma unroll
        for (int q = 0; q < 4; ++q)
            *(float4*)&b[q * 4] = *(const float4*)&Bs[kk][q * 64 + tx * 4];
#pragma unroll
        for (int i = 0; i < 4; ++i)
#pragma unroll
            for (int j = 0; j < 16; ++j)
                acc[i][j] += a[i] * b[(j & 3) * 4 + (j >> 2)] * 0.f + a[i] * b[j] * 0.f + 0.f;
    }
    // NOTE: the line above is replaced below; kept structure for clarity
    // (re-run the real accumulation)
#pragma unroll
    for (int i = 0; i < 4; ++i)
#pragma unroll
        for (int j = 0; j < 16; ++j)
            acc[i][j] = 0.f;
#pragma unroll 4
    for (int kk = 0; kk < 32; ++kk) {
        float a[4];
#pragma unroll
        for (int i = 0; i < 4; ++i) a[i] = As[kk][ty * 4 + i];
        float bq[4][4];
#pragma unroll
        for (int q = 0; q < 4; ++q)
            *(float4*)&bq[q][0] = *(const float4*)&Bs[kk][q * 64 + tx * 4];
#pragma unroll
        for (int i = 0; i < 4; ++i)
#pragma unroll
            for (int q = 0; q < 4; ++q)
#pragma unroll
                for (int jj = 0; jj < 4; ++jj)
                    acc[i][q * 4 + jj] += a[i] * bq[q][jj];
    }

    float att_r[16];
#pragma unroll
    for (int q = 0; q < 4; ++q)
        *(float4*)&att_r[q * 4] = *(const float4*)(att + tx * 16 + q * 4);
    int head = tx >> 2;

#pragma unroll
    for (int i = 0; i < 4; ++i) {
        int e = ty * 4 + i;
        int sn = sidx[e], dn = didx[e];
        float part = 0.f;
#pragma unroll
        for (int q = 0; q < 4; ++q) {
            ushort4 lx = *(const ushort4*)(xlr + (size_t)sn * 512 + tx * 16 + q * 4);
            ushort4 rx = *(const ushort4*)(xlr + (size_t)dn * 512 + 256 + tx * 16 + q * 4);
            float l0 = bf2f(lx.x), l1 = bf2f(lx.y), l2 = bf2f(lx.z), l3 = bf2f(lx.w);
            float r0 = bf2f(rx.x), r1 = bf2f(rx.y), r2 = bf2f(rx.z), r3 = bf2f(rx.w);
            float t0 = acc[i][q * 4 + 0] + l0 + r0; t0 = t0 > 0.f ? t0 : 0.2f * t0;
            float t1 = acc[i][q * 4 + 1] + l1 + r1; t1 = t1 > 0.f ? t1 : 0.2f * t1;
            float t2 = acc[i][q * 4 + 2] + l2 + r2; t2 = t2 > 0.f ? t2 : 0.2f * t2;
            float t3 = acc[i][q * 4 + 3] + l3 + r3; t3 = t3 > 0.f ? t3 : 0.2f * t3;
            part += t0 * att_r[q * 4 + 0] + t1 * att_r[q * 4 + 1]
                  + t2 * att_r[q * 4 + 2] + t3 * att_r[q * 4 + 3];
        }
        part += __shfl_xor(part, 1);
        part += __shfl_xor(part, 2);
        if ((tx & 3) == 0)
            logits[(size_t)(brow + e) * 4 + head] = part;
    }
}

// ---------------------------------------------------------------------------
// One wave per dst node: stream sorted logits, online softmax, gather bf16
// xl[src] from packed xlr, +bias, elu, y = h + hn (in place).
__global__ __launch_bounds__(256) void edge_attn_kernel(
    const int* __restrict__ s_src, const int* __restrict__ offsets,
    const float* __restrict__ logits,
    const float* __restrict__ att, const float* __restrict__ bias,
    const float* __restrict__ eemean,
    const ushortT* __restrict__ xlr, float* __restrict__ h)
{
    int lane = threadIdx.x & 63;
    int d = blockIdx.x * 4 + (threadIdx.x >> 6);
    size_t xbase = (size_t)d * 512 + lane * 4;
    size_t hbase = (size_t)d * 256 + lane * 4;
    int head = lane >> 4;

    ushort4 xlu = *(const ushort4*)(xlr + xbase);
    ushort4 xru = *(const ushort4*)(xlr + xbase + 256);
    float xr0 = bf2f(xru.x), xr1 = bf2f(xru.y), xr2 = bf2f(xru.z), xr3 = bf2f(xru.w);
    float xs0 = bf2f(xlu.x), xs1 = bf2f(xlu.y), xs2 = bf2f(xlu.z), xs3 = bf2f(xlu.w);
    float4 eem = *(const float4*)(eemean + lane * 4);
    float4 at4 = *(const float4*)(att + lane * 4);

    float m = -1e30f, s = 0.f;
    float acc0 = 0.f, acc1 = 0.f, acc2 = 0.f, acc3 = 0.f;
    int beg = offsets[d], end = offsets[d + 1];

    int idx1 = 0;
    ushort4 x_cur = make_ushort4(0, 0, 0, 0);
    float lg_cur = 0.f;
    if (beg < end) {
        int idx0 = s_src[beg];
        x_cur = *(const ushort4*)(xlr + (size_t)idx0 * 512 + lane * 4);
        lg_cur = logits[(size_t)beg * 4 + head];
        if (beg + 1 < end) idx1 = s_src[beg + 1];
    }

    for (int pos = beg; pos < end; ++pos) {
        ushort4 xv = x_cur;
        float lg = lg_cur;
        int np = pos + 1;
        if (np < end) {
            x_cur = *(const ushort4*)(xlr + (size_t)idx1 * 512 + lane * 4);
            lg_cur = logits[(size_t)np * 4 + head];
        }
        if (pos + 2 < end) idx1 = s_src[pos + 2];

        float nm = fmaxf(m, lg);
        float sc = __expf(m - nm);
        float pr = __expf(lg - nm);
        float v0 = bf2f(xv.x), v1 = bf2f(xv.y), v2 = bf2f(xv.z), v3 = bf2f(xv.w);
        s = s * sc + pr;
        acc0 = acc0 * sc + pr * v0;
        acc1 = acc1 * sc + pr * v1;
        acc2 = acc2 * sc + pr * v2;
        acc3 = acc3 * sc + pr * v3;
        m = nm;
    }

    // self-loop edge (xl[d], eemean)
    {
        float t0 = xs0 + xr0 + eem.x; t0 = t0 > 0.f ? t0 : 0.2f * t0;
        float t1 = xs1 + xr1 + eem.y; t1 = t1 > 0.f ? t1 : 0.2f * t1;
        float t2 = xs2 + xr2 + eem.z; t2 = t2 > 0.f ? t2 : 0.2f * t2;
        float t3 = xs3 + xr3 + eem.w; t3 = t3 > 0.f ? t3 : 0.2f * t3;
        float lg = t0 * at4.x + t1 * at4.y + t2 * at4.z + t3 * at4.w;
        lg += __shfl_xor(lg, 1);
        lg += __shfl_xor(lg, 2);
        lg += __shfl_xor(lg, 4);
        lg += __shfl_xor(lg, 8);        // 16-lane head group holds the logit
        float nm = fmaxf(m, lg);
        float sc = __expf(m - nm);
        float pr = __expf(lg - nm);
        s = s * sc + pr;
        acc0 = acc0 * sc + pr * xs0;
        acc1 = acc1 * sc + pr * xs1;
        acc2 = acc2 * sc + pr * xs2;
        acc3 = acc3 * sc + pr * xs3;
    }

    float inv = 1.f / s;
    float4 b4 = *(const float4*)(bias + lane * 4);
    float4 hv = *(const float4*)(h + hbase);
    float o0 = acc0 * inv + b4.x; o0 = o0 > 0.f ? o0 : __expf(o0) - 1.f;
    float o1 = acc1 * inv + b4.y; o1 = o1 > 0.f ? o1 : __expf(o1) - 1.f;
    float o2 = acc2 * inv + b4.z; o2 = o2 > 0.f ? o2 : __expf(o2) - 1.f;
    float o3 = acc3 * inv + b4.w; o3 = o3 > 0.f ? o3 : __expf(o3) - 1.f;
    *(float4*)(h + hbase) = make_float4(hv.x + o0, hv.y + o1, hv.z + o2, hv.w + o3);
}

// ---------------------------------------------------------------------------
// graph-norm stats: sum and sumsq of h, one atomic pair per block
__global__ __launch_bounds__(256) void stats_kernel(const float* __restrict__ h,
                                                    float* __restrict__ stats)
{
    int stride = gridDim.x * blockDim.x;
    int total = N_NODES * 64;      // float4 count
    float ls = 0.f, lq = 0.f;
    for (int i = blockIdx.x * blockDim.x + threadIdx.x; i < total; i += stride) {
        float4 v = ((const float4*)h)[i];
        ls += v.x + v.y + v.z + v.w;
        lq += v.x * v.x + v.y * v.y + v.z * v.z + v.w * v.w;
    }
#pragma unroll
    for (int o = 1; o < 64; o <<= 1) {
        ls += __shfl_xor(ls, o);
        lq += __shfl_xor(lq, o);
    }
    __shared__ float red[8];
    int lane = threadIdx.x & 63, w = threadIdx.x >> 6;
    if (lane == 0) { red[w * 2] = ls; red[w * 2 + 1] = lq; }
    __syncthreads();
    if (threadIdx.x == 0) {
        atomicAdd(&stats[0], red[0] + red[2] + red[4] + red[6]);
        atomicAdd(&stats[1], red[1] + red[3] + red[5] + red[7]);
    }
}

// graph-norm scalars
__global__ void norm_finalize_kernel(float* __restrict__ stats)
{
    float invM = 1.f / ((float)N_NODES * 256.f);
    float mu = stats[0] * invM;
    float var = stats[1] * invM - mu * mu;
    stats[2] = mu;
    stats[3] = rsqrtf(var + EPSN);
}

// h = (h - mu) * scale * g[k] + beta[k], in place
__global__ void normalize_kernel(float* __restrict__ h, const float* __restrict__ g,
                                 const float* __restrict__ beta, const float* __restrict__ stats)
{
    float mu = stats[2], sc = stats[3];
    int stride = gridDim.x * blockDim.x;
    int total = N_NODES * 64;      // float4 count
    for (int i = blockIdx.x * blockDim.x + threadIdx.x; i < total; i += stride) {
        float4 v = ((float4*)h)[i];
        int k = (i & 63) * 4;
        float4 gv = *(const float4*)&g[k];
        float4 bv = *(const float4*)&beta[k];
        v.x = (v.x - mu) * sc * gv.x + bv.x;
        v.y = (v.y - mu) * sc * gv.y + bv.y;
        v.z = (v.z - mu) * sc * gv.z + bv.z;
        v.w = (v.w - mu) * sc * gv.w + bv.w;
        ((float4*)h)[i] = v;
    }
}

// ---------------------------------------------------------------------------
extern "C" void kernel_launch(void* const* d_in, const int* in_sizes, int n_in,
                              void* d_out, int out_size, void* d_ws, size_t ws_size,
                              hipStream_t stream)
{
    (void)in_sizes; (void)n_in; (void)out_size; (void)ws_size;
    const float* x     = (const float*)d_in[0];
    const int*   eidx  = (const int*)d_in[1];
    const float* ea    = (const float*)d_in[2];
    const float* W_in  = (const float*)d_in[3];
    const float* b_in  = (const float*)d_in[4];
    const float* W_out = (const float*)d_in[5];
    const float* b_out = (const float*)d_in[6];
    const float* Wl[2]  = {(const float*)d_in[7],  (const float*)d_in[16]};
    const float* bl[2]  = {(const float*)d_in[8],  (const float*)d_in[17]};
    const float* Wr[2]  = {(const float*)d_in[9],  (const float*)d_in[18]};
    const float* br[2]  = {(const float*)d_in[10], (const float*)d_in[19]};
    const float* We[2]  = {(const float*)d_in[11], (const float*)d_in[20]};
    const float* att[2] = {(const float*)d_in[12], (const float*)d_in[21]};
    const float* bias[2]= {(const float*)d_in[13], (const float*)d_in[22]};
    const float* g[2]   = {(const float*)d_in[14], (const float*)d_in[23]};
    const float* beta[2]= {(const float*)d_in[15], (const float*)d_in[24]};

    // workspace layout (~126 MB)
    char* p = (char*)d_ws;
    auto take = [&](size_t bytes) -> char* {
        char* r = p;
        p += (bytes + 255) & ~(size_t)255;
        return r;
    };
    int*   counts  = (int*)take((size_t)N_NODES * 4);
    int*   cursors = (int*)take((size_t)N_NODES * 4);
    float* ea_acc  = (float*)take(32 * 4);
    float* stats   = (float*)take(8 * 4);
    size_t zero_bytes = (size_t)(p - (char*)d_ws);
    int*   offsets = (int*)take((size_t)(N_NODES + 1) * 4);
    int*   s_src   = (int*)take((size_t)E_EDGES * 4);
    int*   s_dst   = (int*)take((size_t)E_EDGES * 4);
    int*   s_eid   = (int*)take((size_t)E_EDGES * 4);
    float* eemean  = (float*)take(512 * 4);
    ushortT* WtIn  = (ushortT*)take((size_t)256 * 384 * 2);
    ushortT* WtLR0 = (ushortT*)take((size_t)512 * 256 * 2);
    ushortT* WtLR1 = (ushortT*)take((size_t)512 * 256 * 2);
    ushortT* WtOut = (ushortT*)take((size_t)256 * 256 * 2);
    float* fb0     = (float*)take(512 * 4);
    float* fb1     = (float*)take(512 * 4);
    ushortT* xlr   = (ushortT*)take((size_t)N_NODES * 512 * 2);
    float* h       = (float*)take((size_t)N_NODES * 256 * 4);
    float* logits  = (float*)take((size_t)E_EDGES * 4 * 4);

    const ushortT* WtLR[2] = {WtLR0, WtLR1};
    const float* fb[2] = {fb0, fb1};

    const int* srcv = eidx;
    const int* dstv = eidx + E_EDGES;

    hipMemsetAsync(d_ws, 0, zero_bytes, stream);

    ea_accum_kernel<<<512, 256, 0, stream>>>(ea, ea_acc, (long)E_EDGES * 32);
    hist_kernel<<<1024, 256, 0, stream>>>(dstv, counts, E_EDGES);
    scan_kernel<<<1, 1024, 0, stream>>>(counts, offsets, N_NODES);
    scatter_kernel<<<1024, 256, 0, stream>>>(srcv, dstv, offsets, cursors,
                                             s_src, s_dst, s_eid, E_EDGES);
    eemean_kernel<<<1, 512, 0, stream>>>(ea_acc, We[0], We[1], eemean, 1.0f / (float)E_EDGES);

    // weight prep: transpose + bf16
    transpose_bf16_kernel<<<dim3(8, 12), 256, 0, stream>>>(W_in, WtIn, 384, 256);
    transpose_bf16_kernel<<<dim3(8, 8), 256, 0, stream>>>(Wl[0], WtLR0, 256, 256);
    transpose_bf16_kernel<<<dim3(8, 8), 256, 0, stream>>>(Wr[0], WtLR0 + 256 * 256, 256, 256);
    transpose_bf16_kernel<<<dim3(8, 8), 256, 0, stream>>>(Wl[1], WtLR1, 256, 256);
    transpose_bf16_kernel<<<dim3(8, 8), 256, 0, stream>>>(Wr[1], WtLR1 + 256 * 256, 256, 256);
    transpose_bf16_kernel<<<dim3(8, 8), 256, 0, stream>>>(W_out, WtOut, 256, 256);
    fuse_bias_kernel<<<1, 512, 0, stream>>>(bl[0], br[0], fb0);
    fuse_bias_kernel<<<1, 512, 0, stream>>>(bl[1], br[1], fb1);

    // h0 = relu(x @ W_in + b_in), fp32
    mfma_gemm_kernel<<<dim3(391, 2), 256, 0, stream>>>(x, WtIn, b_in, h, nullptr, 384, 256, 1);

    for (int l = 0; l < 2; ++l) {
        // fused [xl|xr] = h @ [Wl|Wr] + [bl|br], bf16 packed
        mfma_gemm_kernel<<<dim3(391, 4), 256, 0, stream>>>(h, WtLR[l], fb[l], nullptr, xlr,
                                                           256, 512, 0);
        edge_logits_kernel<<<E_EDGES / 64, 256, 0, stream>>>(ea, s_eid, s_src, s_dst,
                                                             We[l], att[l], xlr, logits);
        edge_attn_kernel<<<N_NODES / 4, 256, 0, stream>>>(s_src, offsets, logits,
                                                          att[l], bias[l], eemean + l * 256,
                                                          xlr, h);
        stats_kernel<<<2048, 256, 0, stream>>>(h, stats + l * 4);
        norm_finalize_kernel<<<1, 1, 0, stream>>>(stats + l * 4);
        normalize_kernel<<<2048, 256, 0, stream>>>(h, g[l], beta[l], stats + l * 4);
    }
    // out = h @ W_out + b_out, fp32
    mfma_gemm_kernel<<<dim3(391, 2), 256, 0, stream>>>(h, WtOut, b_out, (float*)d_out, nullptr,
                                                       256, 256, 0);
}

// Round 5
// 1372.830 us; speedup vs baseline: 2.7505x; 1.0846x over previous
//
#include <hip/hip_runtime.h>
#include <hip/hip_bf16.h>

// Problem constants (from reference)
#define N_NODES 50000
#define E_EDGES 800000
#define DIN_K   384
#define DH_N    256
#define EPSN    1e-5f

typedef unsigned short ushortT;
typedef __attribute__((ext_vector_type(4))) float f32x4;
typedef __attribute__((ext_vector_type(8))) short bf16x8;

static __device__ __forceinline__ float bf2f(unsigned short u)
{
    return __uint_as_float(((unsigned)u) << 16);
}
static __device__ __forceinline__ unsigned short f2bf(float f)
{
    unsigned u = __float_as_uint(f);
    unsigned r = (u + 0x7fffu + ((u >> 16) & 1u)) >> 16;   // round-nearest-even
    return (unsigned short)r;
}
static __device__ __forceinline__ unsigned pack2(float a, float b)
{
    return (unsigned)f2bf(a) | ((unsigned)f2bf(b) << 16);
}

// ---------------------------------------------------------------------------
// edge_attr column sums (thread always hits column tid%32)
__global__ __launch_bounds__(256) void ea_accum_kernel(const float* __restrict__ ea,
                                                       float* __restrict__ accum, long total)
{
    long stride = (long)gridDim.x * blockDim.x;
    float local = 0.f;
    for (long i = (long)blockIdx.x * blockDim.x + threadIdx.x; i < total; i += stride)
        local += ea[i];
    __shared__ float red[256];
    red[threadIdx.x] = local;
    __syncthreads();
    if (threadIdx.x < 32) {
        float s = 0.f;
#pragma unroll
        for (int r = 0; r < 8; ++r) s += red[r * 32 + threadIdx.x];
        atomicAdd(&accum[threadIdx.x], s);
    }
}

// histogram of dst
__global__ void hist_kernel(const int* __restrict__ dst, int* __restrict__ counts, int E)
{
    int stride = gridDim.x * blockDim.x;
    for (int e = blockIdx.x * blockDim.x + threadIdx.x; e < E; e += stride)
        atomicAdd(&counts[dst[e]], 1);
}

// exclusive scan of counts -> offsets[N+1], single block
__global__ __launch_bounds__(1024) void scan_kernel(const int* __restrict__ counts,
                                                    int* __restrict__ offsets, int Nn)
{
    __shared__ int sdata[1024];
    __shared__ int run_s;
    int tid = threadIdx.x;
    if (tid == 0) run_s = 0;
    __syncthreads();
    for (int base2 = 0; base2 < Nn; base2 += 1024) {
        int i = base2 + tid;
        int v = (i < Nn) ? counts[i] : 0;
        sdata[tid] = v;
        __syncthreads();
        for (int off = 1; off < 1024; off <<= 1) {
            int t = (tid >= off) ? sdata[tid - off] : 0;
            __syncthreads();
            sdata[tid] += t;
            __syncthreads();
        }
        int run = run_s;
        if (i < Nn) offsets[i] = run + sdata[tid] - v;   // exclusive
        int tot = sdata[1023];
        __syncthreads();
        if (tid == 0) run_s = run + tot;
        __syncthreads();
    }
    if (tid == 0) offsets[Nn] = run_s;
}

// scatter edges into dst-sorted order
__global__ void scatter_kernel(const int* __restrict__ src, const int* __restrict__ dst,
                               const int* __restrict__ offsets, int* __restrict__ cursors,
                               int* __restrict__ s_src, int* __restrict__ s_dst,
                               int* __restrict__ s_eid, int E)
{
    int stride = gridDim.x * blockDim.x;
    for (int e = blockIdx.x * blockDim.x + threadIdx.x; e < E; e += stride) {
        int d = dst[e];
        int p = offsets[d] + atomicAdd(&cursors[d], 1);
        s_src[p] = src[e];
        s_dst[p] = d;
        s_eid[p] = e;
    }
}

// self-loop edge feature projections: eemean[layer] = (mean ea) @ We_layer
__global__ void eemean_kernel(const float* __restrict__ accum,
                              const float* __restrict__ We0, const float* __restrict__ We1,
                              float* __restrict__ eemean, float invE)
{
    int tid = threadIdx.x;          // 512 threads
    int layer = tid >> 8, c = tid & 255;
    const float* W = layer ? We1 : We0;
    float s = 0.f;
#pragma unroll
    for (int j = 0; j < 32; ++j) s += accum[j] * invE * W[j * 256 + c];
    eemean[layer * 256 + c] = s;
}

// ---------------------------------------------------------------------------
// weight transpose + bf16 convert: out[n][k] = bf16(in[k][n]); in is [K][N]
__global__ __launch_bounds__(256) void transpose_bf16_kernel(const float* __restrict__ in,
                                                             ushortT* __restrict__ out,
                                                             int K, int N)
{
    __shared__ float tile[32][33];
    int bx = blockIdx.x * 32;     // N dim
    int by = blockIdx.y * 32;     // K dim
    int tx = threadIdx.x & 31, ty = threadIdx.x >> 5;
#pragma unroll
    for (int r = 0; r < 32; r += 8) {
        int k = by + ty + r, n = bx + tx;
        if (k < K && n < N) tile[ty + r][tx] = in[(size_t)k * N + n];
    }
    __syncthreads();
#pragma unroll
    for (int r = 0; r < 32; r += 8) {
        int n = bx + ty + r, k = by + tx;
        if (n < N && k < K) out[(size_t)n * K + k] = f2bf(tile[tx][ty + r]);
    }
}

// fused bias [512] = bl | br
__global__ void fuse_bias_kernel(const float* __restrict__ bl, const float* __restrict__ br,
                                 float* __restrict__ out)
{
    int i = threadIdx.x;
    out[i] = (i < 256) ? bl[i] : br[i - 256];
}

// ---------------------------------------------------------------------------
// MFMA bf16 GEMM: C[row,col] = act(A[row,:K] @ Bt[col,:K]^T + bias[col])
// A fp32 [>=Mvalid][K] (staged->bf16), Bt bf16 [Nn][K] (pre-transposed weights).
// 128x128 tile, BK=32, 256 threads = 4 waves (2x2), 16 mfma_16x16x32 per wave/step.
__global__ __launch_bounds__(256) void mfma_gemm_kernel(
    const float* __restrict__ A, const ushortT* __restrict__ Bt,
    const float* __restrict__ bias, float* __restrict__ Cf,
    ushortT* __restrict__ Cb, int K, int Nn, int act)
{
    __shared__ __align__(16) ushortT As[128 * 32];
    __shared__ __align__(16) ushortT Bs[128 * 32];
    int tid = threadIdx.x;
    int brow = blockIdx.x * 128;
    int bcol = blockIdx.y * 128;
    int lane = tid & 63, w = tid >> 6;
    int wr = w >> 1, wc = w & 1;
    int fr = lane & 15, fq = lane >> 4;

    f32x4 acc[4][4];
#pragma unroll
    for (int i = 0; i < 4; ++i)
#pragma unroll
        for (int j = 0; j < 4; ++j)
            acc[i][j] = (f32x4){0.f, 0.f, 0.f, 0.f};

    int r0 = tid >> 2, g0 = tid & 3;
    int r1 = r0 + 64;
    int arow0 = brow + r0, arow1 = brow + r1;
    bool av0 = arow0 < N_NODES, av1 = arow1 < N_NODES;
    const float* Ap0 = A + (size_t)arow0 * K + g0 * 8;
    const float* Ap1 = A + (size_t)arow1 * K + g0 * 8;
    const ushortT* Bp0 = Bt + (size_t)(bcol + r0) * K + g0 * 8;
    const ushortT* Bp1 = Bt + (size_t)(bcol + r1) * K + g0 * 8;
    uint4* asw0 = (uint4*)&As[(size_t)tid * 8];
    uint4* asw1 = (uint4*)&As[(size_t)(tid + 256) * 8];
    uint4* bsw0 = (uint4*)&Bs[(size_t)tid * 8];
    uint4* bsw1 = (uint4*)&Bs[(size_t)(tid + 256) * 8];

    for (int k0 = 0; k0 < K; k0 += 32) {
        float4 z = make_float4(0.f, 0.f, 0.f, 0.f);
        float4 fa0 = z, fa1 = z, fc0 = z, fc1 = z;
        if (av0) { fa0 = *(const float4*)(Ap0 + k0); fc0 = *(const float4*)(Ap0 + k0 + 4); }
        if (av1) { fa1 = *(const float4*)(Ap1 + k0); fc1 = *(const float4*)(Ap1 + k0 + 4); }
        uint4 ub0 = *(const uint4*)(Bp0 + k0);
        uint4 ub1 = *(const uint4*)(Bp1 + k0);
        uint4 ua0, ua1;
        ua0.x = pack2(fa0.x, fa0.y); ua0.y = pack2(fa0.z, fa0.w);
        ua0.z = pack2(fc0.x, fc0.y); ua0.w = pack2(fc0.z, fc0.w);
        ua1.x = pack2(fa1.x, fa1.y); ua1.y = pack2(fa1.z, fa1.w);
        ua1.z = pack2(fc1.x, fc1.y); ua1.w = pack2(fc1.z, fc1.w);
        __syncthreads();
        *asw0 = ua0; *asw1 = ua1;
        *bsw0 = ub0; *bsw1 = ub1;
        __syncthreads();

        bf16x8 af[4], bfv[4];
#pragma unroll
        for (int mi = 0; mi < 4; ++mi)
            af[mi] = *(bf16x8*)&As[(size_t)(wr * 64 + mi * 16 + fr) * 32 + fq * 8];
#pragma unroll
        for (int ni = 0; ni < 4; ++ni)
            bfv[ni] = *(bf16x8*)&Bs[(size_t)(wc * 64 + ni * 16 + fr) * 32 + fq * 8];
#pragma unroll
        for (int mi = 0; mi < 4; ++mi)
#pragma unroll
            for (int ni = 0; ni < 4; ++ni)
                acc[mi][ni] = __builtin_amdgcn_mfma_f32_16x16x32_bf16(
                    af[mi], bfv[ni], acc[mi][ni], 0, 0, 0);
    }

#pragma unroll
    for (int ni = 0; ni < 4; ++ni) {
        int col = bcol + wc * 64 + ni * 16 + fr;
        float bv = bias[col];
#pragma unroll
        for (int mi = 0; mi < 4; ++mi) {
#pragma unroll
            for (int r = 0; r < 4; ++r) {
                int row = brow + wr * 64 + mi * 16 + fq * 4 + r;
                if (row < N_NODES) {
                    float t = acc[mi][ni][r] + bv;
                    if (act == 1) t = t > 0.f ? t : 0.f;
                    if (Cf) Cf[(size_t)row * Nn + col] = t;
                    if (Cb) Cb[(size_t)row * Nn + col] = f2bf(t);
                }
            }
        }
    }
}

// ---------------------------------------------------------------------------
// MFMA edge logits. Per 64-edge block, 4 waves x 16 edges:
//   ee[ch][edge] = (We^T @ ea[eid]^T) via 16 x mfma_16x16x32_bf16 (K=32, 1 step)
//   m = leaky(ee + xl[src][ch] + xr[dst][ch]); logits[e][h] = sum_ch m*att[ch]
// A = Wet[256][32] bf16 staged in LDS (row stride 40 -> 2-way bank alias, free).
// C frag: lane(fr,fq) reg r -> edge w*16+fr, channel mi*16+fq*4+r.
__global__ __launch_bounds__(256) void edge_logits_kernel(
    const float* __restrict__ ea, const int* __restrict__ s_eid,
    const int* __restrict__ s_src, const int* __restrict__ s_dst,
    const ushortT* __restrict__ Wet, const float* __restrict__ att,
    const ushortT* __restrict__ xlr, float* __restrict__ logits)
{
    __shared__ __align__(16) ushortT Wet_lds[256 * 40];
    __shared__ float att_lds[256];
    __shared__ int sidx[64], didx[64], eidv[64];
    int tid = threadIdx.x;
    int brow = blockIdx.x * 64;

    // stage Wet: 1024 uint4, 4 per thread, padded row stride 40 bf16 (80 B)
#pragma unroll
    for (int t = 0; t < 4; ++t) {
        int f = tid + t * 256;
        int row = f >> 2, q = f & 3;
        *(uint4*)&Wet_lds[row * 40 + q * 8] = *(const uint4*)(Wet + (size_t)row * 32 + q * 8);
    }
    att_lds[tid] = att[tid];
    if (tid < 64) {
        sidx[tid] = s_src[brow + tid];
        didx[tid] = s_dst[brow + tid];
        eidv[tid] = s_eid[brow + tid];
    }
    __syncthreads();

    int lane = tid & 63, w = tid >> 6;
    int fr = lane & 15, fq = lane >> 4;
    int e_lane = w * 16 + fr;

    // b-frag: this lane's edge ea row, floats fq*8..fq*8+7 -> bf16x8
    int eid = eidv[e_lane];
    const float* earow = ea + (size_t)eid * 32 + fq * 8;
    float4 f0 = ((const float4*)earow)[0];
    float4 f1 = ((const float4*)earow)[1];
    union { unsigned u[4]; bf16x8 v; } ub;
    ub.u[0] = pack2(f0.x, f0.y);
    ub.u[1] = pack2(f0.z, f0.w);
    ub.u[2] = pack2(f1.x, f1.y);
    ub.u[3] = pack2(f1.z, f1.w);
    bf16x8 bfrag = ub.v;

    f32x4 acc[16];
#pragma unroll
    for (int mi = 0; mi < 16; ++mi) {
        bf16x8 afrag = *(bf16x8*)&Wet_lds[(mi * 16 + fr) * 40 + fq * 8];
        acc[mi] = __builtin_amdgcn_mfma_f32_16x16x32_bf16(
            afrag, bfrag, (f32x4){0.f, 0.f, 0.f, 0.f}, 0, 0, 0);
    }

    int sn = sidx[e_lane], dn = didx[e_lane];
    const ushortT* lxp = xlr + (size_t)sn * 512;
    const ushortT* rxp = xlr + (size_t)dn * 512 + 256;
    float part[4] = {0.f, 0.f, 0.f, 0.f};
#pragma unroll
    for (int mi = 0; mi < 16; ++mi) {
        int ch = mi * 16 + fq * 4;
        ushort4 lx = *(const ushort4*)(lxp + ch);
        ushort4 rx = *(const ushort4*)(rxp + ch);
        float4 at = *(const float4*)&att_lds[ch];
        float t0 = acc[mi][0] + bf2f(lx.x) + bf2f(rx.x); t0 = t0 > 0.f ? t0 : 0.2f * t0;
        float t1 = acc[mi][1] + bf2f(lx.y) + bf2f(rx.y); t1 = t1 > 0.f ? t1 : 0.2f * t1;
        float t2 = acc[mi][2] + bf2f(lx.z) + bf2f(rx.z); t2 = t2 > 0.f ? t2 : 0.2f * t2;
        float t3 = acc[mi][3] + bf2f(lx.w) + bf2f(rx.w); t3 = t3 > 0.f ? t3 : 0.2f * t3;
        part[mi >> 2] += t0 * at.x + t1 * at.y + t2 * at.z + t3 * at.w;
    }
    // reduce over fq groups (lanes fr, fr+16, fr+32, fr+48)
#pragma unroll
    for (int hh = 0; hh < 4; ++hh) {
        part[hh] += __shfl_xor(part[hh], 16);
        part[hh] += __shfl_xor(part[hh], 32);
    }
    if (fq == 0) {
        float4 o = make_float4(part[0], part[1], part[2], part[3]);
        *(float4*)&logits[(size_t)(brow + e_lane) * 4] = o;
    }
}

// ---------------------------------------------------------------------------
// One wave per dst node: stream sorted logits, online softmax, gather bf16
// xl[src] from packed xlr, +bias, elu, y = h + hn (in place).
__global__ __launch_bounds__(256) void edge_attn_kernel(
    const int* __restrict__ s_src, const int* __restrict__ offsets,
    const float* __restrict__ logits,
    const float* __restrict__ att, const float* __restrict__ bias,
    const float* __restrict__ eemean,
    const ushortT* __restrict__ xlr, float* __restrict__ h)
{
    int lane = threadIdx.x & 63;
    int d = blockIdx.x * 4 + (threadIdx.x >> 6);
    size_t xbase = (size_t)d * 512 + lane * 4;
    size_t hbase = (size_t)d * 256 + lane * 4;
    int head = lane >> 4;

    ushort4 xlu = *(const ushort4*)(xlr + xbase);
    ushort4 xru = *(const ushort4*)(xlr + xbase + 256);
    float xr0 = bf2f(xru.x), xr1 = bf2f(xru.y), xr2 = bf2f(xru.z), xr3 = bf2f(xru.w);
    float xs0 = bf2f(xlu.x), xs1 = bf2f(xlu.y), xs2 = bf2f(xlu.z), xs3 = bf2f(xlu.w);
    float4 eem = *(const float4*)(eemean + lane * 4);
    float4 at4 = *(const float4*)(att + lane * 4);

    float m = -1e30f, s = 0.f;
    float acc0 = 0.f, acc1 = 0.f, acc2 = 0.f, acc3 = 0.f;
    int beg = offsets[d], end = offsets[d + 1];

    int idx1 = 0;
    ushort4 x_cur = make_ushort4(0, 0, 0, 0);
    float lg_cur = 0.f;
    if (beg < end) {
        int idx0 = s_src[beg];
        x_cur = *(const ushort4*)(xlr + (size_t)idx0 * 512 + lane * 4);
        lg_cur = logits[(size_t)beg * 4 + head];
        if (beg + 1 < end) idx1 = s_src[beg + 1];
    }

    for (int pos = beg; pos < end; ++pos) {
        ushort4 xv = x_cur;
        float lg = lg_cur;
        int np = pos + 1;
        if (np < end) {
            x_cur = *(const ushort4*)(xlr + (size_t)idx1 * 512 + lane * 4);
            lg_cur = logits[(size_t)np * 4 + head];
        }
        if (pos + 2 < end) idx1 = s_src[pos + 2];

        float nm = fmaxf(m, lg);
        float sc = __expf(m - nm);
        float pr = __expf(lg - nm);
        float v0 = bf2f(xv.x), v1 = bf2f(xv.y), v2 = bf2f(xv.z), v3 = bf2f(xv.w);
        s = s * sc + pr;
        acc0 = acc0 * sc + pr * v0;
        acc1 = acc1 * sc + pr * v1;
        acc2 = acc2 * sc + pr * v2;
        acc3 = acc3 * sc + pr * v3;
        m = nm;
    }

    // self-loop edge (xl[d], eemean)
    {
        float t0 = xs0 + xr0 + eem.x; t0 = t0 > 0.f ? t0 : 0.2f * t0;
        float t1 = xs1 + xr1 + eem.y; t1 = t1 > 0.f ? t1 : 0.2f * t1;
        float t2 = xs2 + xr2 + eem.z; t2 = t2 > 0.f ? t2 : 0.2f * t2;
        float t3 = xs3 + xr3 + eem.w; t3 = t3 > 0.f ? t3 : 0.2f * t3;
        float lg = t0 * at4.x + t1 * at4.y + t2 * at4.z + t3 * at4.w;
        lg += __shfl_xor(lg, 1);
        lg += __shfl_xor(lg, 2);
        lg += __shfl_xor(lg, 4);
        lg += __shfl_xor(lg, 8);        // 16-lane head group holds the logit
        float nm = fmaxf(m, lg);
        float sc = __expf(m - nm);
        float pr = __expf(lg - nm);
        s = s * sc + pr;
        acc0 = acc0 * sc + pr * xs0;
        acc1 = acc1 * sc + pr * xs1;
        acc2 = acc2 * sc + pr * xs2;
        acc3 = acc3 * sc + pr * xs3;
    }

    float inv = 1.f / s;
    float4 b4 = *(const float4*)(bias + lane * 4);
    float4 hv = *(const float4*)(h + hbase);
    float o0 = acc0 * inv + b4.x; o0 = o0 > 0.f ? o0 : __expf(o0) - 1.f;
    float o1 = acc1 * inv + b4.y; o1 = o1 > 0.f ? o1 : __expf(o1) - 1.f;
    float o2 = acc2 * inv + b4.z; o2 = o2 > 0.f ? o2 : __expf(o2) - 1.f;
    float o3 = acc3 * inv + b4.w; o3 = o3 > 0.f ? o3 : __expf(o3) - 1.f;
    *(float4*)(h + hbase) = make_float4(hv.x + o0, hv.y + o1, hv.z + o2, hv.w + o3);
}

// ---------------------------------------------------------------------------
// graph-norm stats: sum and sumsq of h, one atomic pair per block
__global__ __launch_bounds__(256) void stats_kernel(const float* __restrict__ h,
                                                    float* __restrict__ stats)
{
    int stride = gridDim.x * blockDim.x;
    int total = N_NODES * 64;      // float4 count
    float ls = 0.f, lq = 0.f;
    for (int i = blockIdx.x * blockDim.x + threadIdx.x; i < total; i += stride) {
        float4 v = ((const float4*)h)[i];
        ls += v.x + v.y + v.z + v.w;
        lq += v.x * v.x + v.y * v.y + v.z * v.z + v.w * v.w;
    }
#pragma unroll
    for (int o = 1; o < 64; o <<= 1) {
        ls += __shfl_xor(ls, o);
        lq += __shfl_xor(lq, o);
    }
    __shared__ float red[8];
    int lane = threadIdx.x & 63, w = threadIdx.x >> 6;
    if (lane == 0) { red[w * 2] = ls; red[w * 2 + 1] = lq; }
    __syncthreads();
    if (threadIdx.x == 0) {
        atomicAdd(&stats[0], red[0] + red[2] + red[4] + red[6]);
        atomicAdd(&stats[1], red[1] + red[3] + red[5] + red[7]);
    }
}

// graph-norm scalars
__global__ void norm_finalize_kernel(float* __restrict__ stats)
{
    float invM = 1.f / ((float)N_NODES * 256.f);
    float mu = stats[0] * invM;
    float var = stats[1] * invM - mu * mu;
    stats[2] = mu;
    stats[3] = rsqrtf(var + EPSN);
}

// h = (h - mu) * scale * g[k] + beta[k], in place
__global__ void normalize_kernel(float* __restrict__ h, const float* __restrict__ g,
                                 const float* __restrict__ beta, const float* __restrict__ stats)
{
    float mu = stats[2], sc = stats[3];
    int stride = gridDim.x * blockDim.x;
    int total = N_NODES * 64;      // float4 count
    for (int i = blockIdx.x * blockDim.x + threadIdx.x; i < total; i += stride) {
        float4 v = ((float4*)h)[i];
        int k = (i & 63) * 4;
        float4 gv = *(const float4*)&g[k];
        float4 bv = *(const float4*)&beta[k];
        v.x = (v.x - mu) * sc * gv.x + bv.x;
        v.y = (v.y - mu) * sc * gv.y + bv.y;
        v.z = (v.z - mu) * sc * gv.z + bv.z;
        v.w = (v.w - mu) * sc * gv.w + bv.w;
        ((float4*)h)[i] = v;
    }
}

// ---------------------------------------------------------------------------
extern "C" void kernel_launch(void* const* d_in, const int* in_sizes, int n_in,
                              void* d_out, int out_size, void* d_ws, size_t ws_size,
                              hipStream_t stream)
{
    (void)in_sizes; (void)n_in; (void)out_size; (void)ws_size;
    const float* x     = (const float*)d_in[0];
    const int*   eidx  = (const int*)d_in[1];
    const float* ea    = (const float*)d_in[2];
    const float* W_in  = (const float*)d_in[3];
    const float* b_in  = (const float*)d_in[4];
    const float* W_out = (const float*)d_in[5];
    const float* b_out = (const float*)d_in[6];
    const float* Wl[2]  = {(const float*)d_in[7],  (const float*)d_in[16]};
    const float* bl[2]  = {(const float*)d_in[8],  (const float*)d_in[17]};
    const float* Wr[2]  = {(const float*)d_in[9],  (const float*)d_in[18]};
    const float* br[2]  = {(const float*)d_in[10], (const float*)d_in[19]};
    const float* We[2]  = {(const float*)d_in[11], (const float*)d_in[20]};
    const float* att[2] = {(const float*)d_in[12], (const float*)d_in[21]};
    const float* bias[2]= {(const float*)d_in[13], (const float*)d_in[22]};
    const float* g[2]   = {(const float*)d_in[14], (const float*)d_in[23]};
    const float* beta[2]= {(const float*)d_in[15], (const float*)d_in[24]};

    // workspace layout (~127 MB)
    char* p = (char*)d_ws;
    auto take = [&](size_t bytes) -> char* {
        char* r = p;
        p += (bytes + 255) & ~(size_t)255;
        return r;
    };
    int*   counts  = (int*)take((size_t)N_NODES * 4);
    int*   cursors = (int*)take((size_t)N_NODES * 4);
    float* ea_acc  = (float*)take(32 * 4);
    float* stats   = (float*)take(8 * 4);
    size_t zero_bytes = (size_t)(p - (char*)d_ws);
    int*   offsets = (int*)take((size_t)(N_NODES + 1) * 4);
    int*   s_src   = (int*)take((size_t)E_EDGES * 4);
    int*   s_dst   = (int*)take((size_t)E_EDGES * 4);
    int*   s_eid   = (int*)take((size_t)E_EDGES * 4);
    float* eemean  = (float*)take(512 * 4);
    ushortT* WtIn  = (ushortT*)take((size_t)256 * 384 * 2);
    ushortT* WtLR0 = (ushortT*)take((size_t)512 * 256 * 2);
    ushortT* WtLR1 = (ushortT*)take((size_t)512 * 256 * 2);
    ushortT* WtOut = (ushortT*)take((size_t)256 * 256 * 2);
    ushortT* Wet0  = (ushortT*)take((size_t)256 * 32 * 2);
    ushortT* Wet1  = (ushortT*)take((size_t)256 * 32 * 2);
    float* fb0     = (float*)take(512 * 4);
    float* fb1     = (float*)take(512 * 4);
    ushortT* xlr   = (ushortT*)take((size_t)N_NODES * 512 * 2);
    float* h       = (float*)take((size_t)N_NODES * 256 * 4);
    float* logits  = (float*)take((size_t)E_EDGES * 4 * 4);

    const ushortT* WtLR[2] = {WtLR0, WtLR1};
    const ushortT* Wet[2] = {Wet0, Wet1};
    const float* fb[2] = {fb0, fb1};

    const int* srcv = eidx;
    const int* dstv = eidx + E_EDGES;

    hipMemsetAsync(d_ws, 0, zero_bytes, stream);

    ea_accum_kernel<<<512, 256, 0, stream>>>(ea, ea_acc, (long)E_EDGES * 32);
    hist_kernel<<<1024, 256, 0, stream>>>(dstv, counts, E_EDGES);
    scan_kernel<<<1, 1024, 0, stream>>>(counts, offsets, N_NODES);
    scatter_kernel<<<1024, 256, 0, stream>>>(srcv, dstv, offsets, cursors,
                                             s_src, s_dst, s_eid, E_EDGES);
    eemean_kernel<<<1, 512, 0, stream>>>(ea_acc, We[0], We[1], eemean, 1.0f / (float)E_EDGES);

    // weight prep: transpose + bf16
    transpose_bf16_kernel<<<dim3(8, 12), 256, 0, stream>>>(W_in, WtIn, 384, 256);
    transpose_bf16_kernel<<<dim3(8, 8), 256, 0, stream>>>(Wl[0], WtLR0, 256, 256);
    transpose_bf16_kernel<<<dim3(8, 8), 256, 0, stream>>>(Wr[0], WtLR0 + 256 * 256, 256, 256);
    transpose_bf16_kernel<<<dim3(8, 8), 256, 0, stream>>>(Wl[1], WtLR1, 256, 256);
    transpose_bf16_kernel<<<dim3(8, 8), 256, 0, stream>>>(Wr[1], WtLR1 + 256 * 256, 256, 256);
    transpose_bf16_kernel<<<dim3(8, 8), 256, 0, stream>>>(W_out, WtOut, 256, 256);
    transpose_bf16_kernel<<<dim3(8, 1), 256, 0, stream>>>(We[0], Wet0, 32, 256);
    transpose_bf16_kernel<<<dim3(8, 1), 256, 0, stream>>>(We[1], Wet1, 32, 256);
    fuse_bias_kernel<<<1, 512, 0, stream>>>(bl[0], br[0], fb0);
    fuse_bias_kernel<<<1, 512, 0, stream>>>(bl[1], br[1], fb1);

    // h0 = relu(x @ W_in + b_in), fp32
    mfma_gemm_kernel<<<dim3(391, 2), 256, 0, stream>>>(x, WtIn, b_in, h, nullptr, 384, 256, 1);

    for (int l = 0; l < 2; ++l) {
        // fused [xl|xr] = h @ [Wl|Wr] + [bl|br], bf16 packed
        mfma_gemm_kernel<<<dim3(391, 4), 256, 0, stream>>>(h, WtLR[l], fb[l], nullptr, xlr,
                                                           256, 512, 0);
        edge_logits_kernel<<<E_EDGES / 64, 256, 0, stream>>>(ea, s_eid, s_src, s_dst,
                                                             Wet[l], att[l], xlr, logits);
        edge_attn_kernel<<<N_NODES / 4, 256, 0, stream>>>(s_src, offsets, logits,
                                                          att[l], bias[l], eemean + l * 256,
                                                          xlr, h);
        stats_kernel<<<2048, 256, 0, stream>>>(h, stats + l * 4);
        norm_finalize_kernel<<<1, 1, 0, stream>>>(stats + l * 4);
        normalize_kernel<<<2048, 256, 0, stream>>>(h, g[l], beta[l], stats + l * 4);
    }
    // out = h @ W_out + b_out, fp32
    mfma_gemm_kernel<<<dim3(391, 2), 256, 0, stream>>>(h, WtOut, b_out, (float*)d_out, nullptr,
                                                       256, 256, 0);
}